// Round 8
// baseline (299.346 us; speedup 1.0000x reference)
//
#include <hip/hip_runtime.h>
#include <math.h>

typedef __attribute__((ext_vector_type(8))) short bf16x8;
typedef __attribute__((ext_vector_type(4))) float f32x4;
typedef __attribute__((ext_vector_type(2))) float f32x2;

__device__ inline unsigned short f2bf(float f) {
    union { float f; unsigned u; } v; v.f = f;
    unsigned r = v.u + 0x7FFFu + ((v.u >> 16) & 1u);
    return (unsigned short)(r >> 16);
}
__device__ inline float bf2f(unsigned short s) {
    union { unsigned u; float f; } v; v.u = ((unsigned)s) << 16;
    return v.f;
}

// ---------------------------------------------------------------------------
// Fused prep: deg init + 4x weight transpose/split (saves 4 launches)
// ---------------------------------------------------------------------------
__device__ inline void wconv_elem(const float* __restrict__ W,
                                  unsigned short* __restrict__ Bh,
                                  unsigned short* __restrict__ Bl,
                                  int idx, int NC) {
    int k = idx / NC, n = idx - k * NC;
    float f = W[idx];
    unsigned short h = f2bf(f);
    Bh[n * 256 + k] = h;          // K = 256 for all converted weights
    Bl[n * 256 + k] = f2bf(f - bf2f(h));
}

__global__ __launch_bounds__(256) void k_prep(int* __restrict__ deg, int N,
                                              const float* __restrict__ Wl2,
                                              const float* __restrict__ Wr2,
                                              const float* __restrict__ Wl3,
                                              const float* __restrict__ Wr3,
                                              unsigned short* __restrict__ W2lh,
                                              unsigned short* __restrict__ W2ll,
                                              unsigned short* __restrict__ W2rh,
                                              unsigned short* __restrict__ W2rl,
                                              unsigned short* __restrict__ W3lh,
                                              unsigned short* __restrict__ W3ll,
                                              unsigned short* __restrict__ W3rh,
                                              unsigned short* __restrict__ W3rl) {
    int idx = blockIdx.x * 256 + threadIdx.x;
    if (idx < N) { deg[idx] = 1; return; }
    idx -= N;
    if (idx < 65536) { wconv_elem(Wl2, W2lh, W2ll, idx, 256); return; }
    idx -= 65536;
    if (idx < 65536) { wconv_elem(Wr2, W2rh, W2rl, idx, 256); return; }
    idx -= 65536;
    if (idx < 16384) { wconv_elem(Wl3, W3lh, W3ll, idx, 64); return; }
    idx -= 16384;
    if (idx < 16384) { wconv_elem(Wr3, W3rh, W3rl, idx, 64); }
}

// ---------------------------------------------------------------------------
// CSR construction
// ---------------------------------------------------------------------------
__global__ __launch_bounds__(256) void k_count(const int* __restrict__ dst, int E,
                                               int* __restrict__ deg) {
    int e = blockIdx.x * 256 + threadIdx.x;
    if (e < E) atomicAdd(&deg[dst[e]], 1);
}

__global__ __launch_bounds__(1024) void k_scan1(const int* __restrict__ deg,
                                                int* __restrict__ excl,
                                                int* __restrict__ bsum, int N) {
    __shared__ int wsum[17];
    int t = threadIdx.x, lane = t & 63, wid = t >> 6;
    int idx = blockIdx.x * 1024 + t;
    int v = (idx < N) ? deg[idx] : 0;
    int x = v;
    #pragma unroll
    for (int off = 1; off < 64; off <<= 1) {
        int y = __shfl_up(x, off, 64);
        if (lane >= off) x += y;
    }
    if (lane == 63) wsum[wid] = x;
    __syncthreads();
    if (wid == 0 && lane < 16) {
        int w = wsum[lane];
        int xs = w;
        #pragma unroll
        for (int off = 1; off < 16; off <<= 1) {
            int y = __shfl_up(xs, off, 64);
            if (lane >= off) xs += y;
        }
        wsum[lane] = xs - w;
        if (lane == 15) wsum[16] = xs;
    }
    __syncthreads();
    int incl = x + wsum[wid];
    if (idx < N) excl[idx] = incl - v;
    if (t == 0) bsum[blockIdx.x] = wsum[16];
}

// merged scan2+scan3: each block redundantly prefix-sums bsum (nb <= 64)
__global__ __launch_bounds__(1024) void k_scan23(const int* __restrict__ excl,
                                                 const int* __restrict__ bsum,
                                                 int* __restrict__ rowptr,
                                                 int* __restrict__ cursor, int N, int nb) {
    __shared__ int s_off, s_tot;
    int t = threadIdx.x;
    if (t < 64) {
        int v = (t < nb) ? bsum[t] : 0;
        int x = v;
        #pragma unroll
        for (int off = 1; off < 64; off <<= 1) {
            int y = __shfl_up(x, off, 64);
            if (t >= off) x += y;
        }
        if (t == (int)blockIdx.x) s_off = x - v;  // exclusive offset for this block
        if (t == 63) s_tot = x;
    }
    __syncthreads();
    int idx = blockIdx.x * 1024 + t;
    if (idx < N) {
        int e = excl[idx] + s_off;
        rowptr[idx] = e;
        cursor[idx] = e;
    }
    if (idx == 0) rowptr[N] = s_tot;
}

__global__ __launch_bounds__(256) void k_scatter(const int* __restrict__ src,
                                                 const int* __restrict__ dst,
                                                 int E, int N,
                                                 int* __restrict__ cursor,
                                                 int* __restrict__ col) {
    int idx = blockIdx.x * 256 + threadIdx.x;
    if (idx < E) {
        int d = dst[idx];
        int pos = atomicAdd(&cursor[d], 1);
        col[pos] = src[idx];
    } else if (idx < E + N) {
        int i = idx - E;
        int pos = atomicAdd(&cursor[i], 1);
        col[pos] = i;
    }
}

// ---------------------------------------------------------------------------
// f32 GEMM, dual-weight (layer 1, K=16): C1b(bf16) = A@W1+b1, C2(f32) = A@W2+b2
// ---------------------------------------------------------------------------
__global__ __launch_bounds__(256) void gemm_bias2(const float* __restrict__ A,
                                                  const float* __restrict__ W1,
                                                  const float* __restrict__ b1,
                                                  const float* __restrict__ W2,
                                                  const float* __restrict__ b2,
                                                  unsigned short* __restrict__ C1b,
                                                  float* __restrict__ C2,
                                                  int M, int K, int NC) {
    __shared__ float As[16][68];
    __shared__ float Bs[2][16][68];
    int tid = threadIdx.x;
    int tx = tid & 15, ty = tid >> 4;
    int m0 = blockIdx.x * 64, n0 = blockIdx.y * 64;
    float acc[2][4][4] = {};
    for (int k0 = 0; k0 < K; k0 += 16) {
        #pragma unroll
        for (int i = 0; i < 4; ++i) {
            int idx = tid + i * 256;
            int r = idx >> 4, c = idx & 15;
            int row = m0 + r;
            As[c][r] = (row < M) ? A[(size_t)row * K + k0 + c] : 0.f;
        }
        #pragma unroll
        for (int i = 0; i < 4; ++i) {
            int idx = tid + i * 256;
            int r = idx >> 6, c = idx & 63;
            Bs[0][r][c] = W1[(size_t)(k0 + r) * NC + n0 + c];
            Bs[1][r][c] = W2[(size_t)(k0 + r) * NC + n0 + c];
        }
        __syncthreads();
        #pragma unroll
        for (int k = 0; k < 16; ++k) {
            float a[4], b[4], b2v[4];
            #pragma unroll
            for (int i = 0; i < 4; ++i) a[i] = As[k][ty * 4 + i];
            #pragma unroll
            for (int i = 0; i < 4; ++i) b[i] = Bs[0][k][tx * 4 + i];
            #pragma unroll
            for (int i = 0; i < 4; ++i) b2v[i] = Bs[1][k][tx * 4 + i];
            #pragma unroll
            for (int i = 0; i < 4; ++i)
                #pragma unroll
                for (int j = 0; j < 4; ++j) {
                    acc[0][i][j] += a[i] * b[j];
                    acc[1][i][j] += a[i] * b2v[j];
                }
        }
        __syncthreads();
    }
    #pragma unroll
    for (int i = 0; i < 4; ++i) {
        int row = m0 + ty * 4 + i;
        if (row < M) {
            #pragma unroll
            for (int j = 0; j < 4; ++j) {
                int cn = n0 + tx * 4 + j;
                C1b[(size_t)row * NC + cn] = f2bf(acc[0][i][j] + b1[cn]);
                C2[(size_t)row * NC + cn] = acc[1][i][j] + b2[cn];
            }
        }
    }
}

// ---------------------------------------------------------------------------
// LDS-staged dual-output bf16x3 MFMA GEMM. K=256 fixed.
// ---------------------------------------------------------------------------
#define LDA 40

template<int NF>
__global__ __launch_bounds__(512) void gemm_dual(const unsigned short* __restrict__ Ahg,
                                                 const unsigned short* __restrict__ Alg,
                                                 const unsigned short* __restrict__ B1hg,
                                                 const unsigned short* __restrict__ B1lg,
                                                 const unsigned short* __restrict__ B2hg,
                                                 const unsigned short* __restrict__ B2lg,
                                                 const float* __restrict__ bias1,
                                                 const float* __restrict__ bias2,
                                                 unsigned short* __restrict__ C1b,
                                                 float* __restrict__ C2,
                                                 int M, int NC) {
    const int KD = 256;
    const int BN = NF * 64;
    __shared__ unsigned short Ah[128 * LDA], Al[128 * LDA];
    __shared__ unsigned short Bs[4][BN * LDA];  // B1h, B1l, B2h, B2l

    int tid = threadIdx.x;
    int lane = tid & 63;
    int wid = tid >> 6;
    int m0 = blockIdx.x * 128;
    int n0 = blockIdx.y * BN;
    int wm = (wid >> 2) * 64;
    int wn = (wid & 3) * (NF * 16);
    int r16 = lane & 15;
    int g8 = (lane >> 4) * 8;
    int g = lane >> 4;

    int srow = tid >> 2;
    int schunk = (tid & 3) * 8;
    int arow_g = m0 + srow;
    if (arow_g >= M) arow_g = M - 1;
    const unsigned short* gAh = Ahg + (size_t)arow_g * KD + schunk;
    const unsigned short* gAl = Alg + (size_t)arow_g * KD + schunk;
    bool bact = (NF == 2) || (tid < 256);
    int bcol = (NF == 2) ? srow : (tid >> 2);
    size_t boff = (size_t)(n0 + (bcol < BN ? bcol : 0)) * KD + schunk;
    const unsigned short* gB[4] = { B1hg + boff, B1lg + boff, B2hg + boff, B2lg + boff };

    f32x4 acc[2][4][NF];
    #pragma unroll
    for (int o = 0; o < 2; ++o)
        #pragma unroll
        for (int mf = 0; mf < 4; ++mf)
            #pragma unroll
            for (int nf = 0; nf < NF; ++nf)
                #pragma unroll
                for (int q = 0; q < 4; ++q) acc[o][mf][nf][q] = 0.f;

    bf16x8 sa_h = *(const bf16x8*)gAh;
    bf16x8 sa_l = *(const bf16x8*)gAl;
    bf16x8 sb0, sb1, sb2, sb3;
    if (bact) {
        sb0 = *(const bf16x8*)gB[0];
        sb1 = *(const bf16x8*)gB[1];
        sb2 = *(const bf16x8*)gB[2];
        sb3 = *(const bf16x8*)gB[3];
    }

    for (int k = 0; k < 8; ++k) {
        __syncthreads();
        *(bf16x8*)&Ah[srow * LDA + schunk] = sa_h;
        *(bf16x8*)&Al[srow * LDA + schunk] = sa_l;
        if (bact) {
            *(bf16x8*)&Bs[0][bcol * LDA + schunk] = sb0;
            *(bf16x8*)&Bs[1][bcol * LDA + schunk] = sb1;
            *(bf16x8*)&Bs[2][bcol * LDA + schunk] = sb2;
            *(bf16x8*)&Bs[3][bcol * LDA + schunk] = sb3;
        }
        __syncthreads();
        if (k < 7) {
            int k0n = (k + 1) * 32;
            sa_h = *(const bf16x8*)(gAh + k0n);
            sa_l = *(const bf16x8*)(gAl + k0n);
            if (bact) {
                sb0 = *(const bf16x8*)(gB[0] + k0n);
                sb1 = *(const bf16x8*)(gB[1] + k0n);
                sb2 = *(const bf16x8*)(gB[2] + k0n);
                sb3 = *(const bf16x8*)(gB[3] + k0n);
            }
        }
        bf16x8 ah[4], al[4];
        #pragma unroll
        for (int mf = 0; mf < 4; ++mf) {
            int base = (wm + mf * 16 + r16) * LDA + g8;
            ah[mf] = *(const bf16x8*)&Ah[base];
            al[mf] = *(const bf16x8*)&Al[base];
        }
        #pragma unroll
        for (int o = 0; o < 2; ++o) {
            #pragma unroll
            for (int nf = 0; nf < NF; ++nf) {
                int base = (wn + nf * 16 + r16) * LDA + g8;
                bf16x8 bh = *(const bf16x8*)&Bs[o * 2 + 0][base];
                bf16x8 bl = *(const bf16x8*)&Bs[o * 2 + 1][base];
                #pragma unroll
                for (int mf = 0; mf < 4; ++mf) {
                    acc[o][mf][nf] = __builtin_amdgcn_mfma_f32_16x16x32_bf16(ah[mf], bh, acc[o][mf][nf], 0, 0, 0);
                    acc[o][mf][nf] = __builtin_amdgcn_mfma_f32_16x16x32_bf16(ah[mf], bl, acc[o][mf][nf], 0, 0, 0);
                    acc[o][mf][nf] = __builtin_amdgcn_mfma_f32_16x16x32_bf16(al[mf], bh, acc[o][mf][nf], 0, 0, 0);
                }
            }
        }
    }

    // epilogue: C/D layout col=lane&15, row=(lane>>4)*4+reg (HW-verified)
    #pragma unroll
    for (int nf = 0; nf < NF; ++nf) {
        int cn = n0 + wn + nf * 16 + r16;
        float bv1 = bias1[cn], bv2 = bias2[cn];
        #pragma unroll
        for (int mf = 0; mf < 4; ++mf) {
            #pragma unroll
            for (int r = 0; r < 4; ++r) {
                int row = m0 + wm + mf * 16 + g * 4 + r;
                if (row < M) {
                    C1b[(size_t)row * NC + cn] = f2bf(acc[0][mf][nf][r] + bv1);
                    C2[(size_t)row * NC + cn] = acc[1][mf][nf][r] + bv2;
                }
            }
        }
    }
}

// ---------------------------------------------------------------------------
// GATv2 aggregation H=4, C=64, bf16 gather, packed-f32 math, guarded pipeline.
// Two edges per wave-iteration (one per half-wave, 8 ch/lane).
// Main loop runs only while ALL 16 edges of the window are valid (no checks);
// reload groups are skipped when past the end (kills dup-load waste).
// ---------------------------------------------------------------------------
__global__ __launch_bounds__(128) void gat_agg4(const unsigned short* __restrict__ xlb,
                                                const float* __restrict__ xr,
                                                const float* __restrict__ att,
                                                const float* __restrict__ bias,
                                                const int* __restrict__ rowptr,
                                                const int* __restrict__ col,
                                                unsigned short* __restrict__ Hh,
                                                unsigned short* __restrict__ Hl,
                                                int N) {
    int i = blockIdx.x * 2 + (threadIdx.x >> 6);
    int lane = threadIdx.x & 63;
    if (i >= N) return;
    int sub = lane & 31;
    int half = lane >> 5;
    const float L2E = 1.44269504089f;
    f32x2 xr2[4], a06[4], a04[4];
    {
        float4 a = *(const float4*)(xr + (size_t)i * 256 + sub * 8);
        float4 b = *(const float4*)(xr + (size_t)i * 256 + sub * 8 + 4);
        xr2[0].x = a.x; xr2[0].y = a.y; xr2[1].x = a.z; xr2[1].y = a.w;
        xr2[2].x = b.x; xr2[2].y = b.y; xr2[3].x = b.z; xr2[3].y = b.w;
        float4 c = *(const float4*)(att + sub * 8);
        float4 d = *(const float4*)(att + sub * 8 + 4);
        float av[8] = {c.x, c.y, c.z, c.w, d.x, d.y, d.z, d.w};
        #pragma unroll
        for (int q = 0; q < 4; ++q) {
            a06[q].x = av[2 * q] * (0.6f * L2E);     a06[q].y = av[2 * q + 1] * (0.6f * L2E);
            a04[q].x = av[2 * q] * (0.4f * L2E);     a04[q].y = av[2 * q + 1] * (0.4f * L2E);
        }
    }
    int e0 = rowptr[i], e1 = rowptr[i + 1];
    int nE = e1 - e0;           // >= 1
    int T = (nE + 1) >> 1;      // pair-iterations

    auto jl = [&](int t) -> int {
        int idx = 2 * t + half;
        idx = idx < nE ? idx : nE - 1;
        return col[e0 + idx];
    };
    auto ld = [&](int j) -> bf16x8 {
        return *(const bf16x8*)(xlb + (size_t)j * 256 + sub * 8);
    };

    float ss = 0.f;
    f32x2 acc2[4] = {};

    // CORE: shared math; VCHK=0 -> no validity (main loop, provably in-range)
    #define CORE(R, IT, VCHK) { \
        union { bf16x8 v; unsigned u[4]; } uu; uu.v = (R); \
        f32x2 va_[4]; \
        f32x2 s06_ = {0.f, 0.f}, s04_ = {0.f, 0.f}; \
        _Pragma("unroll") \
        for (int q = 0; q < 4; ++q) { \
            union { unsigned a; float f; } lo_, hi_; \
            lo_.a = uu.u[q] << 16; hi_.a = uu.u[q] & 0xffff0000u; \
            va_[q].x = lo_.f; va_[q].y = hi_.f; \
            f32x2 t_ = va_[q] + xr2[q]; \
            s06_ += t_ * a06[q]; \
            f32x2 ab_; \
            ab_.x = __builtin_fabsf(t_.x); ab_.y = __builtin_fabsf(t_.y); \
            s04_ += ab_ * a04[q]; \
        } \
        f32x2 sc_ = s06_ + s04_; \
        float s_ = sc_.x + sc_.y; \
        s_ += __shfl_xor(s_, 1); \
        s_ += __shfl_xor(s_, 2); \
        s_ += __shfl_xor(s_, 4); \
        float p_ = __builtin_amdgcn_exp2f(s_); \
        if (VCHK) { if ((2 * (IT) + half) >= nE) p_ = 0.f; } \
        ss += p_; \
        f32x2 pp_; pp_.x = p_; pp_.y = p_; \
        _Pragma("unroll") \
        for (int q = 0; q < 4; ++q) acc2[q] += pp_ * va_[q]; \
    }

    int j0 = jl(0), j1 = jl(1), j2 = jl(2), j3 = jl(3);
    bf16x8 r0 = ld(j0), r1 = ld(j1), r2 = ld(j2), r3 = ld(j3);
    bf16x8 r4 = r0, r5 = r0, r6 = r0, r7 = r0;
    if (T > 4) {
        j0 = jl(4); j1 = jl(5); j2 = jl(6); j3 = jl(7);
        r4 = ld(j0); r5 = ld(j1); r6 = ld(j2); r7 = ld(j3);
    }
    if (T > 8) { j0 = jl(8); j1 = jl(9); j2 = jl(10); j3 = jl(11); }

    int t = 0;
    while (t + 9 <= T) {   // pairs t..t+7: all 16 edges provably valid
        CORE(r0, t + 0, 0); CORE(r1, t + 1, 0); CORE(r2, t + 2, 0); CORE(r3, t + 3, 0);
        r0 = ld(j0); r1 = ld(j1); r2 = ld(j2); r3 = ld(j3);   // pairs t+8..t+11 (t+8 < T here)
        bool g2 = (t + 12 < T);
        if (g2) { j0 = jl(t + 12); j1 = jl(t + 13); j2 = jl(t + 14); j3 = jl(t + 15); }
        CORE(r4, t + 4, 0); CORE(r5, t + 5, 0); CORE(r6, t + 6, 0); CORE(r7, t + 7, 0);
        if (g2) {
            r4 = ld(j0); r5 = ld(j1); r6 = ld(j2); r7 = ld(j3);
            j0 = jl(t + 16); j1 = jl(t + 17); j2 = jl(t + 18); j3 = jl(t + 19);
        }
        t += 8;
    }
    if (t + 0 < T) CORE(r0, t + 0, 1);
    if (t + 1 < T) CORE(r1, t + 1, 1);
    if (t + 2 < T) CORE(r2, t + 2, 1);
    if (t + 3 < T) CORE(r3, t + 3, 1);
    if (t + 4 < T) CORE(r4, t + 4, 1);
    if (t + 5 < T) CORE(r5, t + 5, 1);
    if (t + 6 < T) CORE(r6, t + 6, 1);
    if (t + 7 < T) CORE(r7, t + 7, 1);
    #undef CORE

    // cross-half combine
    ss += __shfl_xor(ss, 32);
    #pragma unroll
    for (int q = 0; q < 4; ++q) {
        acc2[q].x += __shfl_xor(acc2[q].x, 32);
        acc2[q].y += __shfl_xor(acc2[q].y, 32);
    }

    if (lane < 32) {
        float inv = 1.f / ss;
        float accf[8];
        #pragma unroll
        for (int q = 0; q < 4; ++q) { accf[2 * q] = acc2[q].x; accf[2 * q + 1] = acc2[q].y; }
        bf16x8 hv, lv;
        #pragma unroll
        for (int c = 0; c < 8; ++c) {
            float o = fmaf(accf[c], inv, bias[sub * 8 + c]);
            o = o > 0.f ? o : __expf(o) - 1.f;   // ELU
            unsigned short h_ = f2bf(o);
            hv[c] = (short)h_;
            lv[c] = (short)f2bf(o - bf2f(h_));
        }
        *(bf16x8*)(Hh + (size_t)i * 256 + sub * 8) = hv;
        *(bf16x8*)(Hl + (size_t)i * 256 + sub * 8) = lv;
    }
}

// ---------------------------------------------------------------------------
// GATv2 aggregation H=1, C=64 (layer 3) + FC [64->2], guarded pipeline.
// FOUR edges per iteration (one per 16-lane quarter, 4 ch/lane).
// ---------------------------------------------------------------------------
__global__ __launch_bounds__(128) void gat_agg1_fc(const unsigned short* __restrict__ xlb,
                                                   const float* __restrict__ xr,
                                                   const float* __restrict__ att,
                                                   const float* __restrict__ bias,
                                                   const float* __restrict__ Wfc,
                                                   const float* __restrict__ bfc,
                                                   const int* __restrict__ rowptr,
                                                   const int* __restrict__ col,
                                                   float* __restrict__ out, int N) {
    int i = blockIdx.x * 2 + (threadIdx.x >> 6);
    int lane = threadIdx.x & 63;
    if (i >= N) return;
    int sub = lane & 15;
    int qh = lane >> 4;
    const float L2E = 1.44269504089f;
    f32x2 xr2[2], a06[2], a04[2];
    {
        float4 a = *(const float4*)(xr + (size_t)i * 64 + sub * 4);
        xr2[0].x = a.x; xr2[0].y = a.y; xr2[1].x = a.z; xr2[1].y = a.w;
        float4 c = *(const float4*)(att + sub * 4);
        float av[4] = {c.x, c.y, c.z, c.w};
        #pragma unroll
        for (int q = 0; q < 2; ++q) {
            a06[q].x = av[2 * q] * (0.6f * L2E);     a06[q].y = av[2 * q + 1] * (0.6f * L2E);
            a04[q].x = av[2 * q] * (0.4f * L2E);     a04[q].y = av[2 * q + 1] * (0.4f * L2E);
        }
    }
    int e0 = rowptr[i], e1 = rowptr[i + 1];
    int nE = e1 - e0;
    int T = (nE + 3) >> 2;

    auto jl = [&](int t) -> int {
        int idx = 4 * t + qh;
        idx = idx < nE ? idx : nE - 1;
        return col[e0 + idx];
    };
    auto ld = [&](int j) -> ushort4 {
        return *(const ushort4*)(xlb + (size_t)j * 64 + sub * 4);
    };

    float ss = 0.f;
    f32x2 acc2[2] = {};

    #define CORE1(R, IT, VCHK) { \
        ushort4 rr_ = (R); \
        f32x2 va_[2]; \
        { union { unsigned a; float f; } c0_, c1_, c2_, c3_; \
          c0_.a = ((unsigned)rr_.x) << 16; c1_.a = ((unsigned)rr_.y) << 16; \
          c2_.a = ((unsigned)rr_.z) << 16; c3_.a = ((unsigned)rr_.w) << 16; \
          va_[0].x = c0_.f; va_[0].y = c1_.f; va_[1].x = c2_.f; va_[1].y = c3_.f; } \
        f32x2 s06_ = {0.f, 0.f}, s04_ = {0.f, 0.f}; \
        _Pragma("unroll") \
        for (int q = 0; q < 2; ++q) { \
            f32x2 t_ = va_[q] + xr2[q]; \
            s06_ += t_ * a06[q]; \
            f32x2 ab_; \
            ab_.x = __builtin_fabsf(t_.x); ab_.y = __builtin_fabsf(t_.y); \
            s04_ += ab_ * a04[q]; \
        } \
        f32x2 sc_ = s06_ + s04_; \
        float s_ = sc_.x + sc_.y; \
        s_ += __shfl_xor(s_, 1); \
        s_ += __shfl_xor(s_, 2); \
        s_ += __shfl_xor(s_, 4); \
        s_ += __shfl_xor(s_, 8); \
        float p_ = __builtin_amdgcn_exp2f(s_); \
        if (VCHK) { if ((4 * (IT) + qh) >= nE) p_ = 0.f; } \
        ss += p_; \
        f32x2 pp_; pp_.x = p_; pp_.y = p_; \
        acc2[0] += pp_ * va_[0]; \
        acc2[1] += pp_ * va_[1]; \
    }

    int j0 = jl(0), j1 = jl(1), j2 = jl(2), j3 = jl(3);
    ushort4 r0 = ld(j0), r1 = ld(j1), r2 = ld(j2), r3 = ld(j3);
    ushort4 r4 = r0, r5 = r0, r6 = r0, r7 = r0;
    if (T > 4) {
        j0 = jl(4); j1 = jl(5); j2 = jl(6); j3 = jl(7);
        r4 = ld(j0); r5 = ld(j1); r6 = ld(j2); r7 = ld(j3);
    }
    if (T > 8) { j0 = jl(8); j1 = jl(9); j2 = jl(10); j3 = jl(11); }

    int t = 0;
    while (t + 9 <= T) {   // quads t..t+7 all valid (4t+31 < nE)
        CORE1(r0, t + 0, 0); CORE1(r1, t + 1, 0); CORE1(r2, t + 2, 0); CORE1(r3, t + 3, 0);
        r0 = ld(j0); r1 = ld(j1); r2 = ld(j2); r3 = ld(j3);
        bool g2 = (t + 12 < T);
        if (g2) { j0 = jl(t + 12); j1 = jl(t + 13); j2 = jl(t + 14); j3 = jl(t + 15); }
        CORE1(r4, t + 4, 0); CORE1(r5, t + 5, 0); CORE1(r6, t + 6, 0); CORE1(r7, t + 7, 0);
        if (g2) {
            r4 = ld(j0); r5 = ld(j1); r6 = ld(j2); r7 = ld(j3);
            j0 = jl(t + 16); j1 = jl(t + 17); j2 = jl(t + 18); j3 = jl(t + 19);
        }
        t += 8;
    }
    if (t + 0 < T) CORE1(r0, t + 0, 1);
    if (t + 1 < T) CORE1(r1, t + 1, 1);
    if (t + 2 < T) CORE1(r2, t + 2, 1);
    if (t + 3 < T) CORE1(r3, t + 3, 1);
    if (t + 4 < T) CORE1(r4, t + 4, 1);
    if (t + 5 < T) CORE1(r5, t + 5, 1);
    if (t + 6 < T) CORE1(r6, t + 6, 1);
    if (t + 7 < T) CORE1(r7, t + 7, 1);
    #undef CORE1

    // cross-quarter combine
    ss += __shfl_xor(ss, 16);
    ss += __shfl_xor(ss, 32);
    float accf[4] = {acc2[0].x, acc2[0].y, acc2[1].x, acc2[1].y};
    #pragma unroll
    for (int c = 0; c < 4; ++c) {
        accf[c] += __shfl_xor(accf[c], 16);
        accf[c] += __shfl_xor(accf[c], 32);
    }

    float inv = 1.f / ss;
    float q0 = 0.f, q1 = 0.f;
    #pragma unroll
    for (int c = 0; c < 4; ++c) {
        float h = fmaf(accf[c], inv, bias[sub * 4 + c]);
        q0 = fmaf(h, Wfc[(sub * 4 + c) * 2 + 0], q0);
        q1 = fmaf(h, Wfc[(sub * 4 + c) * 2 + 1], q1);
    }
    q0 += __shfl_xor(q0, 1); q1 += __shfl_xor(q1, 1);
    q0 += __shfl_xor(q0, 2); q1 += __shfl_xor(q1, 2);
    q0 += __shfl_xor(q0, 4); q1 += __shfl_xor(q1, 4);
    q0 += __shfl_xor(q0, 8); q1 += __shfl_xor(q1, 8);
    if (lane == 0) {
        out[(size_t)i * 2 + 0] = q0 + bfc[0];
        out[(size_t)i * 2 + 1] = q1 + bfc[1];
    }
}

// ---------------------------------------------------------------------------
extern "C" void kernel_launch(void* const* d_in, const int* in_sizes, int n_in,
                              void* d_out, int out_size, void* d_ws, size_t ws_size,
                              hipStream_t stream) {
    const float* x    = (const float*)d_in[0];
    const int*   ei   = (const int*)d_in[1];
    const float* Wl1  = (const float*)d_in[2];
    const float* bl1  = (const float*)d_in[3];
    const float* Wr1  = (const float*)d_in[4];
    const float* br1  = (const float*)d_in[5];
    const float* att1 = (const float*)d_in[6];
    const float* b1   = (const float*)d_in[7];
    const float* Wl2  = (const float*)d_in[8];
    const float* bl2  = (const float*)d_in[9];
    const float* Wr2  = (const float*)d_in[10];
    const float* br2  = (const float*)d_in[11];
    const float* att2 = (const float*)d_in[12];
    const float* b2   = (const float*)d_in[13];
    const float* Wl3  = (const float*)d_in[14];
    const float* bl3  = (const float*)d_in[15];
    const float* Wr3  = (const float*)d_in[16];
    const float* br3  = (const float*)d_in[17];
    const float* att3 = (const float*)d_in[18];
    const float* b3   = (const float*)d_in[19];
    const float* Wfc  = (const float*)d_in[20];
    const float* bfc  = (const float*)d_in[21];
    float* out = (float*)d_out;

    const int N = in_sizes[0] / 16;   // 30000
    const int E = in_sizes[1] / 2;    // 480000
    const int* srcp = ei;
    const int* dstp = ei + E;

    char* ws = (char*)d_ws;
    size_t off = 0;
    auto take = [&](size_t bytes) -> char* {
        char* p = ws + off;
        off = (off + bytes + 255) & ~(size_t)255;
        return p;
    };
    const int nb = (N + 1023) / 1024;
    int* rowptr = (int*)take((size_t)(N + 1) * 4);
    int* cursor = (int*)take((size_t)N * 4);
    int* deg    = (int*)take((size_t)N * 4);
    int* excl   = (int*)take((size_t)N * 4);
    int* bsum   = (int*)take((size_t)(nb + 1) * 4);
    int* col    = (int*)take((size_t)(E + N) * 4);
    unsigned short* xlb = (unsigned short*)take((size_t)N * 256 * 2);
    float* xr   = (float*)take((size_t)N * 256 * 4);
    unsigned short* Hh = (unsigned short*)take((size_t)N * 256 * 2);
    unsigned short* Hl = (unsigned short*)take((size_t)N * 256 * 2);
    unsigned short* W2lh = (unsigned short*)take(256 * 256 * 2);
    unsigned short* W2ll = (unsigned short*)take(256 * 256 * 2);
    unsigned short* W2rh = (unsigned short*)take(256 * 256 * 2);
    unsigned short* W2rl = (unsigned short*)take(256 * 256 * 2);
    unsigned short* W3lh = (unsigned short*)take(256 * 64 * 2);
    unsigned short* W3ll = (unsigned short*)take(256 * 64 * 2);
    unsigned short* W3rh = (unsigned short*)take(256 * 64 * 2);
    unsigned short* W3rl = (unsigned short*)take(256 * 64 * 2);
    (void)ws_size; (void)n_in; (void)out_size;

    // fused prep: deg init + 4 weight conversions
    {
        int total = N + 65536 + 65536 + 16384 + 16384;
        k_prep<<<dim3((total + 255) / 256), dim3(256), 0, stream>>>(
            deg, N, Wl2, Wr2, Wl3, Wr3,
            W2lh, W2ll, W2rh, W2rl, W3lh, W3ll, W3rh, W3rl);
    }
    k_count<<<dim3((E + 255) / 256), dim3(256), 0, stream>>>(dstp, E, deg);
    k_scan1<<<dim3(nb), dim3(1024), 0, stream>>>(deg, excl, bsum, N);
    k_scan23<<<dim3(nb), dim3(1024), 0, stream>>>(excl, bsum, rowptr, cursor, N, nb);
    k_scatter<<<dim3((E + N + 255) / 256), dim3(256), 0, stream>>>(srcp, dstp, E, N, cursor, col);

    dim3 agg_grid((N + 1) / 2);
    int mblk = (N + 127) / 128;

    // layer 1 (K=16): fused dual f32 GEMM (xl -> bf16, xr -> f32)
    gemm_bias2<<<dim3((N + 63) / 64, 4), dim3(256), 0, stream>>>(
        x, Wl1, bl1, Wr1, br1, xlb, xr, N, 16, 256);
    gat_agg4<<<agg_grid, dim3(128), 0, stream>>>(xlb, xr, att1, b1, rowptr, col, Hh, Hl, N);

    // layer 2 (K=256, NC=256): LDS-staged dual bf16x3 MFMA GEMM
    gemm_dual<2><<<dim3(mblk, 2), dim3(512), 0, stream>>>(
        Hh, Hl, W2lh, W2ll, W2rh, W2rl, bl2, br2, xlb, xr, N, 256);
    gat_agg4<<<agg_grid, dim3(128), 0, stream>>>(xlb, xr, att2, b2, rowptr, col, Hh, Hl, N);

    // layer 3 (K=256, NC=64): dual MFMA GEMM + fused agg/FC
    gemm_dual<1><<<dim3(mblk, 1), dim3(512), 0, stream>>>(
        Hh, Hl, W3lh, W3ll, W3rh, W3rl, bl3, br3, xlb, xr, N, 64);
    gat_agg1_fc<<<agg_grid, dim3(128), 0, stream>>>(xlb, xr, att3, b3, Wfc, bfc, rowptr, col, out, N);
}

// Round 9
// 253.755 us; speedup vs baseline: 1.1797x; 1.1797x over previous
//
#include <hip/hip_runtime.h>
#include <math.h>

typedef __attribute__((ext_vector_type(8))) short bf16x8;
typedef __attribute__((ext_vector_type(4))) float f32x4;
typedef __attribute__((ext_vector_type(2))) float f32x2;

__device__ inline unsigned short f2bf(float f) {
    union { float f; unsigned u; } v; v.f = f;
    unsigned r = v.u + 0x7FFFu + ((v.u >> 16) & 1u);
    return (unsigned short)(r >> 16);
}
__device__ inline float bf2f(unsigned short s) {
    union { unsigned u; float f; } v; v.u = ((unsigned)s) << 16;
    return v.f;
}

// ---------------------------------------------------------------------------
// Fused prep: deg init + 4x weight transpose/split (saves 4 launches)
// ---------------------------------------------------------------------------
__device__ inline void wconv_elem(const float* __restrict__ W,
                                  unsigned short* __restrict__ Bh,
                                  unsigned short* __restrict__ Bl,
                                  int idx, int NC) {
    int k = idx / NC, n = idx - k * NC;
    float f = W[idx];
    unsigned short h = f2bf(f);
    Bh[n * 256 + k] = h;          // K = 256 for all converted weights
    Bl[n * 256 + k] = f2bf(f - bf2f(h));
}

__global__ __launch_bounds__(256) void k_prep(int* __restrict__ deg, int N,
                                              const float* __restrict__ Wl2,
                                              const float* __restrict__ Wr2,
                                              const float* __restrict__ Wl3,
                                              const float* __restrict__ Wr3,
                                              unsigned short* __restrict__ W2lh,
                                              unsigned short* __restrict__ W2ll,
                                              unsigned short* __restrict__ W2rh,
                                              unsigned short* __restrict__ W2rl,
                                              unsigned short* __restrict__ W3lh,
                                              unsigned short* __restrict__ W3ll,
                                              unsigned short* __restrict__ W3rh,
                                              unsigned short* __restrict__ W3rl) {
    int idx = blockIdx.x * 256 + threadIdx.x;
    if (idx < N) { deg[idx] = 1; return; }
    idx -= N;
    if (idx < 65536) { wconv_elem(Wl2, W2lh, W2ll, idx, 256); return; }
    idx -= 65536;
    if (idx < 65536) { wconv_elem(Wr2, W2rh, W2rl, idx, 256); return; }
    idx -= 65536;
    if (idx < 16384) { wconv_elem(Wl3, W3lh, W3ll, idx, 64); return; }
    idx -= 16384;
    if (idx < 16384) { wconv_elem(Wr3, W3rh, W3rl, idx, 64); }
}

// ---------------------------------------------------------------------------
// CSR construction
// ---------------------------------------------------------------------------
__global__ __launch_bounds__(256) void k_count(const int* __restrict__ dst, int E,
                                               int* __restrict__ deg) {
    int e = blockIdx.x * 256 + threadIdx.x;
    if (e < E) atomicAdd(&deg[dst[e]], 1);
}

__global__ __launch_bounds__(1024) void k_scan1(const int* __restrict__ deg,
                                                int* __restrict__ excl,
                                                int* __restrict__ bsum, int N) {
    __shared__ int wsum[17];
    int t = threadIdx.x, lane = t & 63, wid = t >> 6;
    int idx = blockIdx.x * 1024 + t;
    int v = (idx < N) ? deg[idx] : 0;
    int x = v;
    #pragma unroll
    for (int off = 1; off < 64; off <<= 1) {
        int y = __shfl_up(x, off, 64);
        if (lane >= off) x += y;
    }
    if (lane == 63) wsum[wid] = x;
    __syncthreads();
    if (wid == 0 && lane < 16) {
        int w = wsum[lane];
        int xs = w;
        #pragma unroll
        for (int off = 1; off < 16; off <<= 1) {
            int y = __shfl_up(xs, off, 64);
            if (lane >= off) xs += y;
        }
        wsum[lane] = xs - w;
        if (lane == 15) wsum[16] = xs;
    }
    __syncthreads();
    int incl = x + wsum[wid];
    if (idx < N) excl[idx] = incl - v;
    if (t == 0) bsum[blockIdx.x] = wsum[16];
}

// merged scan2+scan3: each block redundantly prefix-sums bsum (nb <= 64)
__global__ __launch_bounds__(1024) void k_scan23(const int* __restrict__ excl,
                                                 const int* __restrict__ bsum,
                                                 int* __restrict__ rowptr,
                                                 int* __restrict__ cursor, int N, int nb) {
    __shared__ int s_off, s_tot;
    int t = threadIdx.x;
    if (t < 64) {
        int v = (t < nb) ? bsum[t] : 0;
        int x = v;
        #pragma unroll
        for (int off = 1; off < 64; off <<= 1) {
            int y = __shfl_up(x, off, 64);
            if (t >= off) x += y;
        }
        if (t == (int)blockIdx.x) s_off = x - v;  // exclusive offset for this block
        if (t == 63) s_tot = x;
    }
    __syncthreads();
    int idx = blockIdx.x * 1024 + t;
    if (idx < N) {
        int e = excl[idx] + s_off;
        rowptr[idx] = e;
        cursor[idx] = e;
    }
    if (idx == 0) rowptr[N] = s_tot;
}

__global__ __launch_bounds__(256) void k_scatter(const int* __restrict__ src,
                                                 const int* __restrict__ dst,
                                                 int E, int N,
                                                 int* __restrict__ cursor,
                                                 int* __restrict__ col) {
    int idx = blockIdx.x * 256 + threadIdx.x;
    if (idx < E) {
        int d = dst[idx];
        int pos = atomicAdd(&cursor[d], 1);
        col[pos] = src[idx];
    } else if (idx < E + N) {
        int i = idx - E;
        int pos = atomicAdd(&cursor[i], 1);
        col[pos] = i;
    }
}

// ---------------------------------------------------------------------------
// f32 GEMM, dual-weight (layer 1, K=16): C1b(bf16) = A@W1+b1, C2(f32) = A@W2+b2
// ---------------------------------------------------------------------------
__global__ __launch_bounds__(256) void gemm_bias2(const float* __restrict__ A,
                                                  const float* __restrict__ W1,
                                                  const float* __restrict__ b1,
                                                  const float* __restrict__ W2,
                                                  const float* __restrict__ b2,
                                                  unsigned short* __restrict__ C1b,
                                                  float* __restrict__ C2,
                                                  int M, int K, int NC) {
    __shared__ float As[16][68];
    __shared__ float Bs[2][16][68];
    int tid = threadIdx.x;
    int tx = tid & 15, ty = tid >> 4;
    int m0 = blockIdx.x * 64, n0 = blockIdx.y * 64;
    float acc[2][4][4] = {};
    for (int k0 = 0; k0 < K; k0 += 16) {
        #pragma unroll
        for (int i = 0; i < 4; ++i) {
            int idx = tid + i * 256;
            int r = idx >> 4, c = idx & 15;
            int row = m0 + r;
            As[c][r] = (row < M) ? A[(size_t)row * K + k0 + c] : 0.f;
        }
        #pragma unroll
        for (int i = 0; i < 4; ++i) {
            int idx = tid + i * 256;
            int r = idx >> 6, c = idx & 63;
            Bs[0][r][c] = W1[(size_t)(k0 + r) * NC + n0 + c];
            Bs[1][r][c] = W2[(size_t)(k0 + r) * NC + n0 + c];
        }
        __syncthreads();
        #pragma unroll
        for (int k = 0; k < 16; ++k) {
            float a[4], b[4], b2v[4];
            #pragma unroll
            for (int i = 0; i < 4; ++i) a[i] = As[k][ty * 4 + i];
            #pragma unroll
            for (int i = 0; i < 4; ++i) b[i] = Bs[0][k][tx * 4 + i];
            #pragma unroll
            for (int i = 0; i < 4; ++i) b2v[i] = Bs[1][k][tx * 4 + i];
            #pragma unroll
            for (int i = 0; i < 4; ++i)
                #pragma unroll
                for (int j = 0; j < 4; ++j) {
                    acc[0][i][j] += a[i] * b[j];
                    acc[1][i][j] += a[i] * b2v[j];
                }
        }
        __syncthreads();
    }
    #pragma unroll
    for (int i = 0; i < 4; ++i) {
        int row = m0 + ty * 4 + i;
        if (row < M) {
            #pragma unroll
            for (int j = 0; j < 4; ++j) {
                int cn = n0 + tx * 4 + j;
                C1b[(size_t)row * NC + cn] = f2bf(acc[0][i][j] + b1[cn]);
                C2[(size_t)row * NC + cn] = acc[1][i][j] + b2[cn];
            }
        }
    }
}

// ---------------------------------------------------------------------------
// LDS-staged dual-output bf16x3 MFMA GEMM. K=256 fixed.
// ---------------------------------------------------------------------------
#define LDA 40

template<int NF>
__global__ __launch_bounds__(512) void gemm_dual(const unsigned short* __restrict__ Ahg,
                                                 const unsigned short* __restrict__ Alg,
                                                 const unsigned short* __restrict__ B1hg,
                                                 const unsigned short* __restrict__ B1lg,
                                                 const unsigned short* __restrict__ B2hg,
                                                 const unsigned short* __restrict__ B2lg,
                                                 const float* __restrict__ bias1,
                                                 const float* __restrict__ bias2,
                                                 unsigned short* __restrict__ C1b,
                                                 float* __restrict__ C2,
                                                 int M, int NC) {
    const int KD = 256;
    const int BN = NF * 64;
    __shared__ unsigned short Ah[128 * LDA], Al[128 * LDA];
    __shared__ unsigned short Bs[4][BN * LDA];  // B1h, B1l, B2h, B2l

    int tid = threadIdx.x;
    int lane = tid & 63;
    int wid = tid >> 6;
    int m0 = blockIdx.x * 128;
    int n0 = blockIdx.y * BN;
    int wm = (wid >> 2) * 64;
    int wn = (wid & 3) * (NF * 16);
    int r16 = lane & 15;
    int g8 = (lane >> 4) * 8;
    int g = lane >> 4;

    int srow = tid >> 2;
    int schunk = (tid & 3) * 8;
    int arow_g = m0 + srow;
    if (arow_g >= M) arow_g = M - 1;
    const unsigned short* gAh = Ahg + (size_t)arow_g * KD + schunk;
    const unsigned short* gAl = Alg + (size_t)arow_g * KD + schunk;
    bool bact = (NF == 2) || (tid < 256);
    int bcol = (NF == 2) ? srow : (tid >> 2);
    size_t boff = (size_t)(n0 + (bcol < BN ? bcol : 0)) * KD + schunk;
    const unsigned short* gB[4] = { B1hg + boff, B1lg + boff, B2hg + boff, B2lg + boff };

    f32x4 acc[2][4][NF];
    #pragma unroll
    for (int o = 0; o < 2; ++o)
        #pragma unroll
        for (int mf = 0; mf < 4; ++mf)
            #pragma unroll
            for (int nf = 0; nf < NF; ++nf)
                #pragma unroll
                for (int q = 0; q < 4; ++q) acc[o][mf][nf][q] = 0.f;

    bf16x8 sa_h = *(const bf16x8*)gAh;
    bf16x8 sa_l = *(const bf16x8*)gAl;
    bf16x8 sb0, sb1, sb2, sb3;
    if (bact) {
        sb0 = *(const bf16x8*)gB[0];
        sb1 = *(const bf16x8*)gB[1];
        sb2 = *(const bf16x8*)gB[2];
        sb3 = *(const bf16x8*)gB[3];
    }

    for (int k = 0; k < 8; ++k) {
        __syncthreads();
        *(bf16x8*)&Ah[srow * LDA + schunk] = sa_h;
        *(bf16x8*)&Al[srow * LDA + schunk] = sa_l;
        if (bact) {
            *(bf16x8*)&Bs[0][bcol * LDA + schunk] = sb0;
            *(bf16x8*)&Bs[1][bcol * LDA + schunk] = sb1;
            *(bf16x8*)&Bs[2][bcol * LDA + schunk] = sb2;
            *(bf16x8*)&Bs[3][bcol * LDA + schunk] = sb3;
        }
        __syncthreads();
        if (k < 7) {
            int k0n = (k + 1) * 32;
            sa_h = *(const bf16x8*)(gAh + k0n);
            sa_l = *(const bf16x8*)(gAl + k0n);
            if (bact) {
                sb0 = *(const bf16x8*)(gB[0] + k0n);
                sb1 = *(const bf16x8*)(gB[1] + k0n);
                sb2 = *(const bf16x8*)(gB[2] + k0n);
                sb3 = *(const bf16x8*)(gB[3] + k0n);
            }
        }
        bf16x8 ah[4], al[4];
        #pragma unroll
        for (int mf = 0; mf < 4; ++mf) {
            int base = (wm + mf * 16 + r16) * LDA + g8;
            ah[mf] = *(const bf16x8*)&Ah[base];
            al[mf] = *(const bf16x8*)&Al[base];
        }
        #pragma unroll
        for (int o = 0; o < 2; ++o) {
            #pragma unroll
            for (int nf = 0; nf < NF; ++nf) {
                int base = (wn + nf * 16 + r16) * LDA + g8;
                bf16x8 bh = *(const bf16x8*)&Bs[o * 2 + 0][base];
                bf16x8 bl = *(const bf16x8*)&Bs[o * 2 + 1][base];
                #pragma unroll
                for (int mf = 0; mf < 4; ++mf) {
                    acc[o][mf][nf] = __builtin_amdgcn_mfma_f32_16x16x32_bf16(ah[mf], bh, acc[o][mf][nf], 0, 0, 0);
                    acc[o][mf][nf] = __builtin_amdgcn_mfma_f32_16x16x32_bf16(ah[mf], bl, acc[o][mf][nf], 0, 0, 0);
                    acc[o][mf][nf] = __builtin_amdgcn_mfma_f32_16x16x32_bf16(al[mf], bh, acc[o][mf][nf], 0, 0, 0);
                }
            }
        }
    }

    // epilogue: C/D layout col=lane&15, row=(lane>>4)*4+reg (HW-verified)
    #pragma unroll
    for (int nf = 0; nf < NF; ++nf) {
        int cn = n0 + wn + nf * 16 + r16;
        float bv1 = bias1[cn], bv2 = bias2[cn];
        #pragma unroll
        for (int mf = 0; mf < 4; ++mf) {
            #pragma unroll
            for (int r = 0; r < 4; ++r) {
                int row = m0 + wm + mf * 16 + g * 4 + r;
                if (row < M) {
                    C1b[(size_t)row * NC + cn] = f2bf(acc[0][mf][nf][r] + bv1);
                    C2[(size_t)row * NC + cn] = acc[1][mf][nf][r] + bv2;
                }
            }
        }
    }
}

// ---------------------------------------------------------------------------
// GATv2 aggregation H=4, C=64, bf16 gather, packed-f32 math (R7-verified form:
// unconditional 8-deep pipeline, low VGPR, always-checked PROC).
// ---------------------------------------------------------------------------
__global__ __launch_bounds__(128) void gat_agg4(const unsigned short* __restrict__ xlb,
                                                const float* __restrict__ xr,
                                                const float* __restrict__ att,
                                                const float* __restrict__ bias,
                                                const int* __restrict__ rowptr,
                                                const int* __restrict__ col,
                                                unsigned short* __restrict__ Hh,
                                                unsigned short* __restrict__ Hl,
                                                int N) {
    int i = blockIdx.x * 2 + (threadIdx.x >> 6);
    int lane = threadIdx.x & 63;
    if (i >= N) return;
    int sub = lane & 31;
    int half = lane >> 5;
    const float L2E = 1.44269504089f;
    f32x2 xr2[4], a06[4], a04[4];
    {
        float4 a = *(const float4*)(xr + (size_t)i * 256 + sub * 8);
        float4 b = *(const float4*)(xr + (size_t)i * 256 + sub * 8 + 4);
        xr2[0].x = a.x; xr2[0].y = a.y; xr2[1].x = a.z; xr2[1].y = a.w;
        xr2[2].x = b.x; xr2[2].y = b.y; xr2[3].x = b.z; xr2[3].y = b.w;
        float4 c = *(const float4*)(att + sub * 8);
        float4 d = *(const float4*)(att + sub * 8 + 4);
        float av[8] = {c.x, c.y, c.z, c.w, d.x, d.y, d.z, d.w};
        #pragma unroll
        for (int q = 0; q < 4; ++q) {
            a06[q].x = av[2 * q] * (0.6f * L2E);     a06[q].y = av[2 * q + 1] * (0.6f * L2E);
            a04[q].x = av[2 * q] * (0.4f * L2E);     a04[q].y = av[2 * q + 1] * (0.4f * L2E);
        }
    }
    int e0 = rowptr[i], e1 = rowptr[i + 1];
    int nE = e1 - e0;           // >= 1
    int T = (nE + 1) >> 1;      // pair-iterations

    auto jl = [&](int t) -> int {
        int idx = 2 * t + half;
        idx = idx < nE ? idx : nE - 1;
        return col[e0 + idx];
    };
    auto ld = [&](int j) -> bf16x8 {
        return *(const bf16x8*)(xlb + (size_t)j * 256 + sub * 8);
    };

    float ss = 0.f;
    f32x2 acc2[4] = {};

    #define PROC(R, IT) { \
        union { bf16x8 v; unsigned u[4]; } uu; uu.v = (R); \
        f32x2 va_[4]; \
        f32x2 s06_ = {0.f, 0.f}, s04_ = {0.f, 0.f}; \
        _Pragma("unroll") \
        for (int q = 0; q < 4; ++q) { \
            union { unsigned a; float f; } lo_, hi_; \
            lo_.a = uu.u[q] << 16; hi_.a = uu.u[q] & 0xffff0000u; \
            va_[q].x = lo_.f; va_[q].y = hi_.f; \
            f32x2 t_ = va_[q] + xr2[q]; \
            s06_ += t_ * a06[q]; \
            f32x2 ab_; \
            ab_.x = __builtin_fabsf(t_.x); ab_.y = __builtin_fabsf(t_.y); \
            s04_ += ab_ * a04[q]; \
        } \
        f32x2 sc_ = s06_ + s04_; \
        float s_ = sc_.x + sc_.y; \
        s_ += __shfl_xor(s_, 1); \
        s_ += __shfl_xor(s_, 2); \
        s_ += __shfl_xor(s_, 4); \
        bool valid_ = (2 * (IT) + half) < nE; \
        float p_ = valid_ ? __builtin_amdgcn_exp2f(s_) : 0.f; \
        ss += p_; \
        f32x2 pp_; pp_.x = p_; pp_.y = p_; \
        _Pragma("unroll") \
        for (int q = 0; q < 4; ++q) acc2[q] += pp_ * va_[q]; \
    }

    int j0 = jl(0), j1 = jl(1), j2 = jl(2), j3 = jl(3);
    bf16x8 r0 = ld(j0), r1 = ld(j1), r2 = ld(j2), r3 = ld(j3);
    int j4 = jl(4), j5 = jl(5), j6 = jl(6), j7 = jl(7);
    bf16x8 r4 = ld(j4), r5 = ld(j5), r6 = ld(j6), r7 = ld(j7);
    j0 = jl(8); j1 = jl(9); j2 = jl(10); j3 = jl(11);

    int t = 0;
    while (t + 8 <= T) {
        PROC(r0, t + 0); PROC(r1, t + 1); PROC(r2, t + 2); PROC(r3, t + 3);
        r0 = ld(j0); r1 = ld(j1); r2 = ld(j2); r3 = ld(j3);
        j0 = jl(t + 12); j1 = jl(t + 13); j2 = jl(t + 14); j3 = jl(t + 15);
        PROC(r4, t + 4); PROC(r5, t + 5); PROC(r6, t + 6); PROC(r7, t + 7);
        r4 = ld(j0); r5 = ld(j1); r6 = ld(j2); r7 = ld(j3);
        j0 = jl(t + 16); j1 = jl(t + 17); j2 = jl(t + 18); j3 = jl(t + 19);
        t += 8;
    }
    if (t + 0 < T) PROC(r0, t + 0);
    if (t + 1 < T) PROC(r1, t + 1);
    if (t + 2 < T) PROC(r2, t + 2);
    if (t + 3 < T) PROC(r3, t + 3);
    if (t + 4 < T) PROC(r4, t + 4);
    if (t + 5 < T) PROC(r5, t + 5);
    if (t + 6 < T) PROC(r6, t + 6);
    if (t + 7 < T) PROC(r7, t + 7);
    #undef PROC

    // cross-half combine
    ss += __shfl_xor(ss, 32);
    #pragma unroll
    for (int q = 0; q < 4; ++q) {
        acc2[q].x += __shfl_xor(acc2[q].x, 32);
        acc2[q].y += __shfl_xor(acc2[q].y, 32);
    }

    if (lane < 32) {
        float inv = 1.f / ss;
        float accf[8];
        #pragma unroll
        for (int q = 0; q < 4; ++q) { accf[2 * q] = acc2[q].x; accf[2 * q + 1] = acc2[q].y; }
        bf16x8 hv, lv;
        #pragma unroll
        for (int c = 0; c < 8; ++c) {
            float o = fmaf(accf[c], inv, bias[sub * 8 + c]);
            o = o > 0.f ? o : __expf(o) - 1.f;   // ELU
            unsigned short h_ = f2bf(o);
            hv[c] = (short)h_;
            lv[c] = (short)f2bf(o - bf2f(h_));
        }
        *(bf16x8*)(Hh + (size_t)i * 256 + sub * 8) = hv;
        *(bf16x8*)(Hl + (size_t)i * 256 + sub * 8) = lv;
    }
}

// ---------------------------------------------------------------------------
// GATv2 aggregation H=1, C=64 (layer 3) + FC [64->2] (R7-verified form).
// ---------------------------------------------------------------------------
__global__ __launch_bounds__(128) void gat_agg1_fc(const unsigned short* __restrict__ xlb,
                                                   const float* __restrict__ xr,
                                                   const float* __restrict__ att,
                                                   const float* __restrict__ bias,
                                                   const float* __restrict__ Wfc,
                                                   const float* __restrict__ bfc,
                                                   const int* __restrict__ rowptr,
                                                   const int* __restrict__ col,
                                                   float* __restrict__ out, int N) {
    int i = blockIdx.x * 2 + (threadIdx.x >> 6);
    int lane = threadIdx.x & 63;
    if (i >= N) return;
    int sub = lane & 15;
    int qh = lane >> 4;
    const float L2E = 1.44269504089f;
    f32x2 xr2[2], a06[2], a04[2];
    {
        float4 a = *(const float4*)(xr + (size_t)i * 64 + sub * 4);
        xr2[0].x = a.x; xr2[0].y = a.y; xr2[1].x = a.z; xr2[1].y = a.w;
        float4 c = *(const float4*)(att + sub * 4);
        float av[4] = {c.x, c.y, c.z, c.w};
        #pragma unroll
        for (int q = 0; q < 2; ++q) {
            a06[q].x = av[2 * q] * (0.6f * L2E);     a06[q].y = av[2 * q + 1] * (0.6f * L2E);
            a04[q].x = av[2 * q] * (0.4f * L2E);     a04[q].y = av[2 * q + 1] * (0.4f * L2E);
        }
    }
    int e0 = rowptr[i], e1 = rowptr[i + 1];
    int nE = e1 - e0;
    int T = (nE + 3) >> 2;

    auto jl = [&](int t) -> int {
        int idx = 4 * t + qh;
        idx = idx < nE ? idx : nE - 1;
        return col[e0 + idx];
    };
    auto ld = [&](int j) -> ushort4 {
        return *(const ushort4*)(xlb + (size_t)j * 64 + sub * 4);
    };

    float ss = 0.f;
    f32x2 acc2[2] = {};

    #define PROC1(R, IT) { \
        ushort4 rr_ = (R); \
        f32x2 va_[2]; \
        { union { unsigned a; float f; } c0_, c1_, c2_, c3_; \
          c0_.a = ((unsigned)rr_.x) << 16; c1_.a = ((unsigned)rr_.y) << 16; \
          c2_.a = ((unsigned)rr_.z) << 16; c3_.a = ((unsigned)rr_.w) << 16; \
          va_[0].x = c0_.f; va_[0].y = c1_.f; va_[1].x = c2_.f; va_[1].y = c3_.f; } \
        f32x2 s06_ = {0.f, 0.f}, s04_ = {0.f, 0.f}; \
        _Pragma("unroll") \
        for (int q = 0; q < 2; ++q) { \
            f32x2 t_ = va_[q] + xr2[q]; \
            s06_ += t_ * a06[q]; \
            f32x2 ab_; \
            ab_.x = __builtin_fabsf(t_.x); ab_.y = __builtin_fabsf(t_.y); \
            s04_ += ab_ * a04[q]; \
        } \
        f32x2 sc_ = s06_ + s04_; \
        float s_ = sc_.x + sc_.y; \
        s_ += __shfl_xor(s_, 1); \
        s_ += __shfl_xor(s_, 2); \
        s_ += __shfl_xor(s_, 4); \
        s_ += __shfl_xor(s_, 8); \
        bool valid_ = (4 * (IT) + qh) < nE; \
        float p_ = valid_ ? __builtin_amdgcn_exp2f(s_) : 0.f; \
        ss += p_; \
        f32x2 pp_; pp_.x = p_; pp_.y = p_; \
        acc2[0] += pp_ * va_[0]; \
        acc2[1] += pp_ * va_[1]; \
    }

    int j0 = jl(0), j1 = jl(1), j2 = jl(2), j3 = jl(3);
    ushort4 r0 = ld(j0), r1 = ld(j1), r2 = ld(j2), r3 = ld(j3);
    int j4 = jl(4), j5 = jl(5), j6 = jl(6), j7 = jl(7);
    ushort4 r4 = ld(j4), r5 = ld(j5), r6 = ld(j6), r7 = ld(j7);
    j0 = jl(8); j1 = jl(9); j2 = jl(10); j3 = jl(11);

    int t = 0;
    while (t + 8 <= T) {
        PROC1(r0, t + 0); PROC1(r1, t + 1); PROC1(r2, t + 2); PROC1(r3, t + 3);
        r0 = ld(j0); r1 = ld(j1); r2 = ld(j2); r3 = ld(j3);
        j0 = jl(t + 12); j1 = jl(t + 13); j2 = jl(t + 14); j3 = jl(t + 15);
        PROC1(r4, t + 4); PROC1(r5, t + 5); PROC1(r6, t + 6); PROC1(r7, t + 7);
        r4 = ld(j0); r5 = ld(j1); r6 = ld(j2); r7 = ld(j3);
        j0 = jl(t + 16); j1 = jl(t + 17); j2 = jl(t + 18); j3 = jl(t + 19);
        t += 8;
    }
    if (t + 0 < T) PROC1(r0, t + 0);
    if (t + 1 < T) PROC1(r1, t + 1);
    if (t + 2 < T) PROC1(r2, t + 2);
    if (t + 3 < T) PROC1(r3, t + 3);
    if (t + 4 < T) PROC1(r4, t + 4);
    if (t + 5 < T) PROC1(r5, t + 5);
    if (t + 6 < T) PROC1(r6, t + 6);
    if (t + 7 < T) PROC1(r7, t + 7);
    #undef PROC1

    // cross-quarter combine
    ss += __shfl_xor(ss, 16);
    ss += __shfl_xor(ss, 32);
    float accf[4] = {acc2[0].x, acc2[0].y, acc2[1].x, acc2[1].y};
    #pragma unroll
    for (int c = 0; c < 4; ++c) {
        accf[c] += __shfl_xor(accf[c], 16);
        accf[c] += __shfl_xor(accf[c], 32);
    }

    float inv = 1.f / ss;
    float q0 = 0.f, q1 = 0.f;
    #pragma unroll
    for (int c = 0; c < 4; ++c) {
        float h = fmaf(accf[c], inv, bias[sub * 4 + c]);
        q0 = fmaf(h, Wfc[(sub * 4 + c) * 2 + 0], q0);
        q1 = fmaf(h, Wfc[(sub * 4 + c) * 2 + 1], q1);
    }
    q0 += __shfl_xor(q0, 1); q1 += __shfl_xor(q1, 1);
    q0 += __shfl_xor(q0, 2); q1 += __shfl_xor(q1, 2);
    q0 += __shfl_xor(q0, 4); q1 += __shfl_xor(q1, 4);
    q0 += __shfl_xor(q0, 8); q1 += __shfl_xor(q1, 8);
    if (lane == 0) {
        out[(size_t)i * 2 + 0] = q0 + bfc[0];
        out[(size_t)i * 2 + 1] = q1 + bfc[1];
    }
}

// ---------------------------------------------------------------------------
extern "C" void kernel_launch(void* const* d_in, const int* in_sizes, int n_in,
                              void* d_out, int out_size, void* d_ws, size_t ws_size,
                              hipStream_t stream) {
    const float* x    = (const float*)d_in[0];
    const int*   ei   = (const int*)d_in[1];
    const float* Wl1  = (const float*)d_in[2];
    const float* bl1  = (const float*)d_in[3];
    const float* Wr1  = (const float*)d_in[4];
    const float* br1  = (const float*)d_in[5];
    const float* att1 = (const float*)d_in[6];
    const float* b1   = (const float*)d_in[7];
    const float* Wl2  = (const float*)d_in[8];
    const float* bl2  = (const float*)d_in[9];
    const float* Wr2  = (const float*)d_in[10];
    const float* br2  = (const float*)d_in[11];
    const float* att2 = (const float*)d_in[12];
    const float* b2   = (const float*)d_in[13];
    const float* Wl3  = (const float*)d_in[14];
    const float* bl3  = (const float*)d_in[15];
    const float* Wr3  = (const float*)d_in[16];
    const float* br3  = (const float*)d_in[17];
    const float* att3 = (const float*)d_in[18];
    const float* b3   = (const float*)d_in[19];
    const float* Wfc  = (const float*)d_in[20];
    const float* bfc  = (const float*)d_in[21];
    float* out = (float*)d_out;

    const int N = in_sizes[0] / 16;   // 30000
    const int E = in_sizes[1] / 2;    // 480000
    const int* srcp = ei;
    const int* dstp = ei + E;

    char* ws = (char*)d_ws;
    size_t off = 0;
    auto take = [&](size_t bytes) -> char* {
        char* p = ws + off;
        off = (off + bytes + 255) & ~(size_t)255;
        return p;
    };
    const int nb = (N + 1023) / 1024;
    int* rowptr = (int*)take((size_t)(N + 1) * 4);
    int* cursor = (int*)take((size_t)N * 4);
    int* deg    = (int*)take((size_t)N * 4);
    int* excl   = (int*)take((size_t)N * 4);
    int* bsum   = (int*)take((size_t)(nb + 1) * 4);
    int* col    = (int*)take((size_t)(E + N) * 4);
    unsigned short* xlb = (unsigned short*)take((size_t)N * 256 * 2);
    float* xr   = (float*)take((size_t)N * 256 * 4);
    unsigned short* Hh = (unsigned short*)take((size_t)N * 256 * 2);
    unsigned short* Hl = (unsigned short*)take((size_t)N * 256 * 2);
    unsigned short* W2lh = (unsigned short*)take(256 * 256 * 2);
    unsigned short* W2ll = (unsigned short*)take(256 * 256 * 2);
    unsigned short* W2rh = (unsigned short*)take(256 * 256 * 2);
    unsigned short* W2rl = (unsigned short*)take(256 * 256 * 2);
    unsigned short* W3lh = (unsigned short*)take(256 * 64 * 2);
    unsigned short* W3ll = (unsigned short*)take(256 * 64 * 2);
    unsigned short* W3rh = (unsigned short*)take(256 * 64 * 2);
    unsigned short* W3rl = (unsigned short*)take(256 * 64 * 2);
    (void)ws_size; (void)n_in; (void)out_size;

    // fused prep: deg init + 4 weight conversions
    {
        int total = N + 65536 + 65536 + 16384 + 16384;
        k_prep<<<dim3((total + 255) / 256), dim3(256), 0, stream>>>(
            deg, N, Wl2, Wr2, Wl3, Wr3,
            W2lh, W2ll, W2rh, W2rl, W3lh, W3ll, W3rh, W3rl);
    }
    k_count<<<dim3((E + 255) / 256), dim3(256), 0, stream>>>(dstp, E, deg);
    k_scan1<<<dim3(nb), dim3(1024), 0, stream>>>(deg, excl, bsum, N);
    k_scan23<<<dim3(nb), dim3(1024), 0, stream>>>(excl, bsum, rowptr, cursor, N, nb);
    k_scatter<<<dim3((E + N + 255) / 256), dim3(256), 0, stream>>>(srcp, dstp, E, N, cursor, col);

    dim3 agg_grid((N + 1) / 2);
    int mblk = (N + 127) / 128;

    // layer 1 (K=16): fused dual f32 GEMM (xl -> bf16, xr -> f32)
    gemm_bias2<<<dim3((N + 63) / 64, 4), dim3(256), 0, stream>>>(
        x, Wl1, bl1, Wr1, br1, xlb, xr, N, 16, 256);
    gat_agg4<<<agg_grid, dim3(128), 0, stream>>>(xlb, xr, att1, b1, rowptr, col, Hh, Hl, N);

    // layer 2 (K=256, NC=256): LDS-staged dual bf16x3 MFMA GEMM
    gemm_dual<2><<<dim3(mblk, 2), dim3(512), 0, stream>>>(
        Hh, Hl, W2lh, W2ll, W2rh, W2rl, bl2, br2, xlb, xr, N, 256);
    gat_agg4<<<agg_grid, dim3(128), 0, stream>>>(xlb, xr, att2, b2, rowptr, col, Hh, Hl, N);

    // layer 3 (K=256, NC=64): dual MFMA GEMM + fused agg/FC
    gemm_dual<1><<<dim3(mblk, 1), dim3(512), 0, stream>>>(
        Hh, Hl, W3lh, W3ll, W3rh, W3rl, bl3, br3, xlb, xr, N, 64);
    gat_agg1_fc<<<agg_grid, dim3(128), 0, stream>>>(xlb, xr, att3, b3, Wfc, bfc, rowptr, col, out, N);
}

// Round 10
// 242.898 us; speedup vs baseline: 1.2324x; 1.0447x over previous
//
#include <hip/hip_runtime.h>
#include <math.h>

typedef __attribute__((ext_vector_type(8))) short bf16x8;
typedef __attribute__((ext_vector_type(4))) float f32x4;
typedef __attribute__((ext_vector_type(2))) float f32x2;

__device__ inline unsigned short f2bf(float f) {
    union { float f; unsigned u; } v; v.f = f;
    unsigned r = v.u + 0x7FFFu + ((v.u >> 16) & 1u);
    return (unsigned short)(r >> 16);
}
__device__ inline float bf2f(unsigned short s) {
    union { unsigned u; float f; } v; v.u = ((unsigned)s) << 16;
    return v.f;
}

// ---------------------------------------------------------------------------
// Fused prep: deg init + 4x weight transpose/split
// ---------------------------------------------------------------------------
__device__ inline void wconv_elem(const float* __restrict__ W,
                                  unsigned short* __restrict__ Bh,
                                  unsigned short* __restrict__ Bl,
                                  int idx, int NC) {
    int k = idx / NC, n = idx - k * NC;
    float f = W[idx];
    unsigned short h = f2bf(f);
    Bh[n * 256 + k] = h;          // K = 256 for all converted weights
    Bl[n * 256 + k] = f2bf(f - bf2f(h));
}

__global__ __launch_bounds__(256) void k_prep(int* __restrict__ deg, int N,
                                              const float* __restrict__ Wl2,
                                              const float* __restrict__ Wr2,
                                              const float* __restrict__ Wl3,
                                              const float* __restrict__ Wr3,
                                              unsigned short* __restrict__ W2lh,
                                              unsigned short* __restrict__ W2ll,
                                              unsigned short* __restrict__ W2rh,
                                              unsigned short* __restrict__ W2rl,
                                              unsigned short* __restrict__ W3lh,
                                              unsigned short* __restrict__ W3ll,
                                              unsigned short* __restrict__ W3rh,
                                              unsigned short* __restrict__ W3rl) {
    int idx = blockIdx.x * 256 + threadIdx.x;
    if (idx < N) { deg[idx] = 1; return; }
    idx -= N;
    if (idx < 65536) { wconv_elem(Wl2, W2lh, W2ll, idx, 256); return; }
    idx -= 65536;
    if (idx < 65536) { wconv_elem(Wr2, W2rh, W2rl, idx, 256); return; }
    idx -= 65536;
    if (idx < 16384) { wconv_elem(Wl3, W3lh, W3ll, idx, 64); return; }
    idx -= 16384;
    if (idx < 16384) { wconv_elem(Wr3, W3rh, W3rl, idx, 64); }
}

// ---------------------------------------------------------------------------
// CSR construction
// ---------------------------------------------------------------------------
__global__ __launch_bounds__(256) void k_count(const int* __restrict__ dst, int E,
                                               int* __restrict__ deg) {
    int e = blockIdx.x * 256 + threadIdx.x;
    if (e < E) atomicAdd(&deg[dst[e]], 1);
}

__global__ __launch_bounds__(1024) void k_scan1(const int* __restrict__ deg,
                                                int* __restrict__ excl,
                                                int* __restrict__ bsum, int N) {
    __shared__ int wsum[17];
    int t = threadIdx.x, lane = t & 63, wid = t >> 6;
    int idx = blockIdx.x * 1024 + t;
    int v = (idx < N) ? deg[idx] : 0;
    int x = v;
    #pragma unroll
    for (int off = 1; off < 64; off <<= 1) {
        int y = __shfl_up(x, off, 64);
        if (lane >= off) x += y;
    }
    if (lane == 63) wsum[wid] = x;
    __syncthreads();
    if (wid == 0 && lane < 16) {
        int w = wsum[lane];
        int xs = w;
        #pragma unroll
        for (int off = 1; off < 16; off <<= 1) {
            int y = __shfl_up(xs, off, 64);
            if (lane >= off) xs += y;
        }
        wsum[lane] = xs - w;
        if (lane == 15) wsum[16] = xs;
    }
    __syncthreads();
    int incl = x + wsum[wid];
    if (idx < N) excl[idx] = incl - v;
    if (t == 0) bsum[blockIdx.x] = wsum[16];
}

// merged scan2+scan3: each block redundantly prefix-sums bsum (nb <= 64)
__global__ __launch_bounds__(1024) void k_scan23(const int* __restrict__ excl,
                                                 const int* __restrict__ bsum,
                                                 int* __restrict__ rowptr,
                                                 int* __restrict__ cursor, int N, int nb) {
    __shared__ int s_off, s_tot;
    int t = threadIdx.x;
    if (t < 64) {
        int v = (t < nb) ? bsum[t] : 0;
        int x = v;
        #pragma unroll
        for (int off = 1; off < 64; off <<= 1) {
            int y = __shfl_up(x, off, 64);
            if (t >= off) x += y;
        }
        if (t == (int)blockIdx.x) s_off = x - v;
        if (t == 63) s_tot = x;
    }
    __syncthreads();
    int idx = blockIdx.x * 1024 + t;
    if (idx < N) {
        int e = excl[idx] + s_off;
        rowptr[idx] = e;
        cursor[idx] = e;
    }
    if (idx == 0) rowptr[N] = s_tot;
}

// scatter + zero-fill 64-entry col slack (for agg base-pointer overreads)
__global__ __launch_bounds__(256) void k_scatter(const int* __restrict__ src,
                                                 const int* __restrict__ dst,
                                                 int E, int N,
                                                 int* __restrict__ cursor,
                                                 int* __restrict__ col) {
    int idx = blockIdx.x * 256 + threadIdx.x;
    if (idx < E) {
        int d = dst[idx];
        int pos = atomicAdd(&cursor[d], 1);
        col[pos] = src[idx];
    } else if (idx < E + N) {
        int i = idx - E;
        int pos = atomicAdd(&cursor[i], 1);
        col[pos] = i;
    } else if (idx < E + N + 64) {
        col[idx] = 0;   // safe slack
    }
}

// ---------------------------------------------------------------------------
// f32 GEMM, dual-weight (layer 1, K=16). Grid is (4, mtiles): adjacent blocks
// share the same A tile -> same/nearby XCD L2 -> A fetched once.
// ---------------------------------------------------------------------------
__global__ __launch_bounds__(256) void gemm_bias2(const float* __restrict__ A,
                                                  const float* __restrict__ W1,
                                                  const float* __restrict__ b1,
                                                  const float* __restrict__ W2,
                                                  const float* __restrict__ b2,
                                                  unsigned short* __restrict__ C1b,
                                                  float* __restrict__ C2,
                                                  int M, int K, int NC) {
    __shared__ float As[16][68];
    __shared__ float Bs[2][16][68];
    int tid = threadIdx.x;
    int tx = tid & 15, ty = tid >> 4;
    int m0 = blockIdx.y * 64, n0 = blockIdx.x * 64;
    float acc[2][4][4] = {};
    for (int k0 = 0; k0 < K; k0 += 16) {
        #pragma unroll
        for (int i = 0; i < 4; ++i) {
            int idx = tid + i * 256;
            int r = idx >> 4, c = idx & 15;
            int row = m0 + r;
            As[c][r] = (row < M) ? A[(size_t)row * K + k0 + c] : 0.f;
        }
        #pragma unroll
        for (int i = 0; i < 4; ++i) {
            int idx = tid + i * 256;
            int r = idx >> 6, c = idx & 63;
            Bs[0][r][c] = W1[(size_t)(k0 + r) * NC + n0 + c];
            Bs[1][r][c] = W2[(size_t)(k0 + r) * NC + n0 + c];
        }
        __syncthreads();
        #pragma unroll
        for (int k = 0; k < 16; ++k) {
            float a[4], b[4], b2v[4];
            #pragma unroll
            for (int i = 0; i < 4; ++i) a[i] = As[k][ty * 4 + i];
            #pragma unroll
            for (int i = 0; i < 4; ++i) b[i] = Bs[0][k][tx * 4 + i];
            #pragma unroll
            for (int i = 0; i < 4; ++i) b2v[i] = Bs[1][k][tx * 4 + i];
            #pragma unroll
            for (int i = 0; i < 4; ++i)
                #pragma unroll
                for (int j = 0; j < 4; ++j) {
                    acc[0][i][j] += a[i] * b[j];
                    acc[1][i][j] += a[i] * b2v[j];
                }
        }
        __syncthreads();
    }
    #pragma unroll
    for (int i = 0; i < 4; ++i) {
        int row = m0 + ty * 4 + i;
        if (row < M) {
            #pragma unroll
            for (int j = 0; j < 4; ++j) {
                int cn = n0 + tx * 4 + j;
                C1b[(size_t)row * NC + cn] = f2bf(acc[0][i][j] + b1[cn]);
                C2[(size_t)row * NC + cn] = acc[1][i][j] + b2[cn];
            }
        }
    }
}

// ---------------------------------------------------------------------------
// LDS-staged dual-output bf16x3 MFMA GEMM. K=256 fixed.
// Grid is (ntiles, mtiles): blocks sharing an A panel are dispatch-adjacent.
// ---------------------------------------------------------------------------
#define LDA 40

template<int NF>
__global__ __launch_bounds__(512) void gemm_dual(const unsigned short* __restrict__ Ahg,
                                                 const unsigned short* __restrict__ Alg,
                                                 const unsigned short* __restrict__ B1hg,
                                                 const unsigned short* __restrict__ B1lg,
                                                 const unsigned short* __restrict__ B2hg,
                                                 const unsigned short* __restrict__ B2lg,
                                                 const float* __restrict__ bias1,
                                                 const float* __restrict__ bias2,
                                                 unsigned short* __restrict__ C1b,
                                                 float* __restrict__ C2,
                                                 int M, int NC) {
    const int KD = 256;
    const int BN = NF * 64;
    __shared__ unsigned short Ah[128 * LDA], Al[128 * LDA];
    __shared__ unsigned short Bs[4][BN * LDA];  // B1h, B1l, B2h, B2l

    int tid = threadIdx.x;
    int lane = tid & 63;
    int wid = tid >> 6;
    int m0 = blockIdx.y * 128;
    int n0 = blockIdx.x * BN;
    int wm = (wid >> 2) * 64;
    int wn = (wid & 3) * (NF * 16);
    int r16 = lane & 15;
    int g8 = (lane >> 4) * 8;
    int g = lane >> 4;

    int srow = tid >> 2;
    int schunk = (tid & 3) * 8;
    int arow_g = m0 + srow;
    if (arow_g >= M) arow_g = M - 1;
    const unsigned short* gAh = Ahg + (size_t)arow_g * KD + schunk;
    const unsigned short* gAl = Alg + (size_t)arow_g * KD + schunk;
    bool bact = (NF == 2) || (tid < 256);
    int bcol = (NF == 2) ? srow : (tid >> 2);
    size_t boff = (size_t)(n0 + (bcol < BN ? bcol : 0)) * KD + schunk;
    const unsigned short* gB[4] = { B1hg + boff, B1lg + boff, B2hg + boff, B2lg + boff };

    f32x4 acc[2][4][NF];
    #pragma unroll
    for (int o = 0; o < 2; ++o)
        #pragma unroll
        for (int mf = 0; mf < 4; ++mf)
            #pragma unroll
            for (int nf = 0; nf < NF; ++nf)
                #pragma unroll
                for (int q = 0; q < 4; ++q) acc[o][mf][nf][q] = 0.f;

    bf16x8 sa_h = *(const bf16x8*)gAh;
    bf16x8 sa_l = *(const bf16x8*)gAl;
    bf16x8 sb0, sb1, sb2, sb3;
    if (bact) {
        sb0 = *(const bf16x8*)gB[0];
        sb1 = *(const bf16x8*)gB[1];
        sb2 = *(const bf16x8*)gB[2];
        sb3 = *(const bf16x8*)gB[3];
    }

    for (int k = 0; k < 8; ++k) {
        __syncthreads();
        *(bf16x8*)&Ah[srow * LDA + schunk] = sa_h;
        *(bf16x8*)&Al[srow * LDA + schunk] = sa_l;
        if (bact) {
            *(bf16x8*)&Bs[0][bcol * LDA + schunk] = sb0;
            *(bf16x8*)&Bs[1][bcol * LDA + schunk] = sb1;
            *(bf16x8*)&Bs[2][bcol * LDA + schunk] = sb2;
            *(bf16x8*)&Bs[3][bcol * LDA + schunk] = sb3;
        }
        __syncthreads();
        if (k < 7) {
            int k0n = (k + 1) * 32;
            sa_h = *(const bf16x8*)(gAh + k0n);
            sa_l = *(const bf16x8*)(gAl + k0n);
            if (bact) {
                sb0 = *(const bf16x8*)(gB[0] + k0n);
                sb1 = *(const bf16x8*)(gB[1] + k0n);
                sb2 = *(const bf16x8*)(gB[2] + k0n);
                sb3 = *(const bf16x8*)(gB[3] + k0n);
            }
        }
        bf16x8 ah[4], al[4];
        #pragma unroll
        for (int mf = 0; mf < 4; ++mf) {
            int base = (wm + mf * 16 + r16) * LDA + g8;
            ah[mf] = *(const bf16x8*)&Ah[base];
            al[mf] = *(const bf16x8*)&Al[base];
        }
        #pragma unroll
        for (int o = 0; o < 2; ++o) {
            #pragma unroll
            for (int nf = 0; nf < NF; ++nf) {
                int base = (wn + nf * 16 + r16) * LDA + g8;
                bf16x8 bh = *(const bf16x8*)&Bs[o * 2 + 0][base];
                bf16x8 bl = *(const bf16x8*)&Bs[o * 2 + 1][base];
                #pragma unroll
                for (int mf = 0; mf < 4; ++mf) {
                    acc[o][mf][nf] = __builtin_amdgcn_mfma_f32_16x16x32_bf16(ah[mf], bh, acc[o][mf][nf], 0, 0, 0);
                    acc[o][mf][nf] = __builtin_amdgcn_mfma_f32_16x16x32_bf16(ah[mf], bl, acc[o][mf][nf], 0, 0, 0);
                    acc[o][mf][nf] = __builtin_amdgcn_mfma_f32_16x16x32_bf16(al[mf], bh, acc[o][mf][nf], 0, 0, 0);
                }
            }
        }
    }

    // epilogue: C/D layout col=lane&15, row=(lane>>4)*4+reg (HW-verified)
    #pragma unroll
    for (int nf = 0; nf < NF; ++nf) {
        int cn = n0 + wn + nf * 16 + r16;
        float bv1 = bias1[cn], bv2 = bias2[cn];
        #pragma unroll
        for (int mf = 0; mf < 4; ++mf) {
            #pragma unroll
            for (int r = 0; r < 4; ++r) {
                int row = m0 + wm + mf * 16 + g * 4 + r;
                if (row < M) {
                    C1b[(size_t)row * NC + cn] = f2bf(acc[0][mf][nf][r] + bv1);
                    C2[(size_t)row * NC + cn] = acc[1][mf][nf][r] + bv2;
                }
            }
        }
    }
}

// ---------------------------------------------------------------------------
// GATv2 aggregation H=4, C=64, bf16 gather, packed-f32 math.
// One wave per node (64-thread block). Contiguous per-half edge streams:
// half h processes edges [h*T, h*T+lim); index loads cb[min(t,limL)]
// (clamped -> dup loads are L1 hits); validity is a single t<lim compare.
// ---------------------------------------------------------------------------
__global__ __launch_bounds__(64) void gat_agg4(const unsigned short* __restrict__ xlb,
                                               const float* __restrict__ xr,
                                               const float* __restrict__ att,
                                               const float* __restrict__ bias,
                                               const int* __restrict__ rowptr,
                                               const int* __restrict__ col,
                                               unsigned short* __restrict__ Hh,
                                               unsigned short* __restrict__ Hl,
                                               int N) {
    int i = blockIdx.x;
    int lane = threadIdx.x;
    int sub = lane & 31;
    int half = lane >> 5;
    const float L2E = 1.44269504089f;
    f32x2 xr2[4], a06[4], a04[4];
    {
        float4 a = *(const float4*)(xr + (size_t)i * 256 + sub * 8);
        float4 b = *(const float4*)(xr + (size_t)i * 256 + sub * 8 + 4);
        xr2[0].x = a.x; xr2[0].y = a.y; xr2[1].x = a.z; xr2[1].y = a.w;
        xr2[2].x = b.x; xr2[2].y = b.y; xr2[3].x = b.z; xr2[3].y = b.w;
        float4 c = *(const float4*)(att + sub * 8);
        float4 d = *(const float4*)(att + sub * 8 + 4);
        float av[8] = {c.x, c.y, c.z, c.w, d.x, d.y, d.z, d.w};
        #pragma unroll
        for (int q = 0; q < 4; ++q) {
            a06[q].x = av[2 * q] * (0.6f * L2E);     a06[q].y = av[2 * q + 1] * (0.6f * L2E);
            a04[q].x = av[2 * q] * (0.4f * L2E);     a04[q].y = av[2 * q + 1] * (0.4f * L2E);
        }
    }
    int e0 = rowptr[i], e1 = rowptr[i + 1];
    int nE = e1 - e0;           // >= 1
    int T = (nE + 1) >> 1;      // per-half iterations
    int lim = half ? (nE - T) : T;      // valid iterations for this half
    int limL = lim > 0 ? lim - 1 : 0;   // clamp target for index loads
    const int* cb = col + e0 + (half ? T : 0);

    auto jl = [&](int t) -> int { return cb[t < limL ? t : limL]; };
    auto ld = [&](int j) -> bf16x8 {
        return *(const bf16x8*)(xlb + (size_t)j * 256 + sub * 8);
    };

    float ss = 0.f;
    f32x2 acc2[4] = {};

    #define PROC(R, IT) { \
        union { bf16x8 v; unsigned u[4]; } uu; uu.v = (R); \
        f32x2 va_[4]; \
        f32x2 s06_ = {0.f, 0.f}, s04_ = {0.f, 0.f}; \
        _Pragma("unroll") \
        for (int q = 0; q < 4; ++q) { \
            union { unsigned a; float f; } lo_, hi_; \
            lo_.a = uu.u[q] << 16; hi_.a = uu.u[q] & 0xffff0000u; \
            va_[q].x = lo_.f; va_[q].y = hi_.f; \
            f32x2 t_ = va_[q] + xr2[q]; \
            s06_ += t_ * a06[q]; \
            f32x2 ab_; \
            ab_.x = __builtin_fabsf(t_.x); ab_.y = __builtin_fabsf(t_.y); \
            s04_ += ab_ * a04[q]; \
        } \
        f32x2 sc_ = s06_ + s04_; \
        float s_ = sc_.x + sc_.y; \
        s_ += __shfl_xor(s_, 1); \
        s_ += __shfl_xor(s_, 2); \
        s_ += __shfl_xor(s_, 4); \
        bool valid_ = (IT) < lim; \
        float p_ = valid_ ? __builtin_amdgcn_exp2f(s_) : 0.f; \
        ss += p_; \
        f32x2 pp_; pp_.x = p_; pp_.y = p_; \
        _Pragma("unroll") \
        for (int q = 0; q < 4; ++q) acc2[q] += pp_ * va_[q]; \
    }

    int j0 = jl(0), j1 = jl(1), j2 = jl(2), j3 = jl(3);
    bf16x8 r0 = ld(j0), r1 = ld(j1), r2 = ld(j2), r3 = ld(j3);
    int j4 = jl(4), j5 = jl(5), j6 = jl(6), j7 = jl(7);
    bf16x8 r4 = ld(j4), r5 = ld(j5), r6 = ld(j6), r7 = ld(j7);
    j0 = jl(8); j1 = jl(9); j2 = jl(10); j3 = jl(11);

    int t = 0;
    while (t + 8 <= T) {
        PROC(r0, t + 0); PROC(r1, t + 1); PROC(r2, t + 2); PROC(r3, t + 3);
        r0 = ld(j0); r1 = ld(j1); r2 = ld(j2); r3 = ld(j3);
        j0 = jl(t + 12); j1 = jl(t + 13); j2 = jl(t + 14); j3 = jl(t + 15);
        PROC(r4, t + 4); PROC(r5, t + 5); PROC(r6, t + 6); PROC(r7, t + 7);
        r4 = ld(j0); r5 = ld(j1); r6 = ld(j2); r7 = ld(j3);
        j0 = jl(t + 16); j1 = jl(t + 17); j2 = jl(t + 18); j3 = jl(t + 19);
        t += 8;
    }
    if (t + 0 < T) PROC(r0, t + 0);
    if (t + 1 < T) PROC(r1, t + 1);
    if (t + 2 < T) PROC(r2, t + 2);
    if (t + 3 < T) PROC(r3, t + 3);
    if (t + 4 < T) PROC(r4, t + 4);
    if (t + 5 < T) PROC(r5, t + 5);
    if (t + 6 < T) PROC(r6, t + 6);
    if (t + 7 < T) PROC(r7, t + 7);
    #undef PROC

    // cross-half combine
    ss += __shfl_xor(ss, 32);
    #pragma unroll
    for (int q = 0; q < 4; ++q) {
        acc2[q].x += __shfl_xor(acc2[q].x, 32);
        acc2[q].y += __shfl_xor(acc2[q].y, 32);
    }

    if (lane < 32) {
        float inv = 1.f / ss;
        float accf[8];
        #pragma unroll
        for (int q = 0; q < 4; ++q) { accf[2 * q] = acc2[q].x; accf[2 * q + 1] = acc2[q].y; }
        bf16x8 hv, lv;
        #pragma unroll
        for (int c = 0; c < 8; ++c) {
            float o = fmaf(accf[c], inv, bias[sub * 8 + c]);
            o = o > 0.f ? o : __expf(o) - 1.f;   // ELU
            unsigned short h_ = f2bf(o);
            hv[c] = (short)h_;
            lv[c] = (short)f2bf(o - bf2f(h_));
        }
        *(bf16x8*)(Hh + (size_t)i * 256 + sub * 8) = hv;
        *(bf16x8*)(Hl + (size_t)i * 256 + sub * 8) = lv;
    }
}

// ---------------------------------------------------------------------------
// GATv2 aggregation H=1, C=64 (layer 3) + FC [64->2].
// Contiguous per-quarter edge streams (quarter q: edges [q*T, q*T+lim)).
// ---------------------------------------------------------------------------
__global__ __launch_bounds__(64) void gat_agg1_fc(const unsigned short* __restrict__ xlb,
                                                  const float* __restrict__ xr,
                                                  const float* __restrict__ att,
                                                  const float* __restrict__ bias,
                                                  const float* __restrict__ Wfc,
                                                  const float* __restrict__ bfc,
                                                  const int* __restrict__ rowptr,
                                                  const int* __restrict__ col,
                                                  float* __restrict__ out, int N) {
    int i = blockIdx.x;
    int lane = threadIdx.x;
    int sub = lane & 15;
    int qh = lane >> 4;
    const float L2E = 1.44269504089f;
    f32x2 xr2[2], a06[2], a04[2];
    {
        float4 a = *(const float4*)(xr + (size_t)i * 64 + sub * 4);
        xr2[0].x = a.x; xr2[0].y = a.y; xr2[1].x = a.z; xr2[1].y = a.w;
        float4 c = *(const float4*)(att + sub * 4);
        float av[4] = {c.x, c.y, c.z, c.w};
        #pragma unroll
        for (int q = 0; q < 2; ++q) {
            a06[q].x = av[2 * q] * (0.6f * L2E);     a06[q].y = av[2 * q + 1] * (0.6f * L2E);
            a04[q].x = av[2 * q] * (0.4f * L2E);     a04[q].y = av[2 * q + 1] * (0.4f * L2E);
        }
    }
    int e0 = rowptr[i], e1 = rowptr[i + 1];
    int nE = e1 - e0;
    int T = (nE + 3) >> 2;
    int lim = nE - qh * T;
    lim = lim < 0 ? 0 : (lim > T ? T : lim);
    int limL = lim > 0 ? lim - 1 : 0;
    const int* cb = col + e0 + qh * T;

    auto jl = [&](int t) -> int { return cb[t < limL ? t : limL]; };
    auto ld = [&](int j) -> ushort4 {
        return *(const ushort4*)(xlb + (size_t)j * 64 + sub * 4);
    };

    float ss = 0.f;
    f32x2 acc2[2] = {};

    #define PROC1(R, IT) { \
        ushort4 rr_ = (R); \
        f32x2 va_[2]; \
        { union { unsigned a; float f; } c0_, c1_, c2_, c3_; \
          c0_.a = ((unsigned)rr_.x) << 16; c1_.a = ((unsigned)rr_.y) << 16; \
          c2_.a = ((unsigned)rr_.z) << 16; c3_.a = ((unsigned)rr_.w) << 16; \
          va_[0].x = c0_.f; va_[0].y = c1_.f; va_[1].x = c2_.f; va_[1].y = c3_.f; } \
        f32x2 s06_ = {0.f, 0.f}, s04_ = {0.f, 0.f}; \
        _Pragma("unroll") \
        for (int q = 0; q < 2; ++q) { \
            f32x2 t_ = va_[q] + xr2[q]; \
            s06_ += t_ * a06[q]; \
            f32x2 ab_; \
            ab_.x = __builtin_fabsf(t_.x); ab_.y = __builtin_fabsf(t_.y); \
            s04_ += ab_ * a04[q]; \
        } \
        f32x2 sc_ = s06_ + s04_; \
        float s_ = sc_.x + sc_.y; \
        s_ += __shfl_xor(s_, 1); \
        s_ += __shfl_xor(s_, 2); \
        s_ += __shfl_xor(s_, 4); \
        s_ += __shfl_xor(s_, 8); \
        bool valid_ = (IT) < lim; \
        float p_ = valid_ ? __builtin_amdgcn_exp2f(s_) : 0.f; \
        ss += p_; \
        f32x2 pp_; pp_.x = p_; pp_.y = p_; \
        acc2[0] += pp_ * va_[0]; \
        acc2[1] += pp_ * va_[1]; \
    }

    int j0 = jl(0), j1 = jl(1), j2 = jl(2), j3 = jl(3);
    ushort4 r0 = ld(j0), r1 = ld(j1), r2 = ld(j2), r3 = ld(j3);
    int j4 = jl(4), j5 = jl(5), j6 = jl(6), j7 = jl(7);
    ushort4 r4 = ld(j4), r5 = ld(j5), r6 = ld(j6), r7 = ld(j7);
    j0 = jl(8); j1 = jl(9); j2 = jl(10); j3 = jl(11);

    int t = 0;
    while (t + 8 <= T) {
        PROC1(r0, t + 0); PROC1(r1, t + 1); PROC1(r2, t + 2); PROC1(r3, t + 3);
        r0 = ld(j0); r1 = ld(j1); r2 = ld(j2); r3 = ld(j3);
        j0 = jl(t + 12); j1 = jl(t + 13); j2 = jl(t + 14); j3 = jl(t + 15);
        PROC1(r4, t + 4); PROC1(r5, t + 5); PROC1(r6, t + 6); PROC1(r7, t + 7);
        r4 = ld(j0); r5 = ld(j1); r6 = ld(j2); r7 = ld(j3);
        j0 = jl(t + 16); j1 = jl(t + 17); j2 = jl(t + 18); j3 = jl(t + 19);
        t += 8;
    }
    if (t + 0 < T) PROC1(r0, t + 0);
    if (t + 1 < T) PROC1(r1, t + 1);
    if (t + 2 < T) PROC1(r2, t + 2);
    if (t + 3 < T) PROC1(r3, t + 3);
    if (t + 4 < T) PROC1(r4, t + 4);
    if (t + 5 < T) PROC1(r5, t + 5);
    if (t + 6 < T) PROC1(r6, t + 6);
    if (t + 7 < T) PROC1(r7, t + 7);
    #undef PROC1

    // cross-quarter combine
    ss += __shfl_xor(ss, 16);
    ss += __shfl_xor(ss, 32);
    float accf[4] = {acc2[0].x, acc2[0].y, acc2[1].x, acc2[1].y};
    #pragma unroll
    for (int c = 0; c < 4; ++c) {
        accf[c] += __shfl_xor(accf[c], 16);
        accf[c] += __shfl_xor(accf[c], 32);
    }

    float inv = 1.f / ss;
    float q0 = 0.f, q1 = 0.f;
    #pragma unroll
    for (int c = 0; c < 4; ++c) {
        float h = fmaf(accf[c], inv, bias[sub * 4 + c]);
        q0 = fmaf(h, Wfc[(sub * 4 + c) * 2 + 0], q0);
        q1 = fmaf(h, Wfc[(sub * 4 + c) * 2 + 1], q1);
    }
    q0 += __shfl_xor(q0, 1); q1 += __shfl_xor(q1, 1);
    q0 += __shfl_xor(q0, 2); q1 += __shfl_xor(q1, 2);
    q0 += __shfl_xor(q0, 4); q1 += __shfl_xor(q1, 4);
    q0 += __shfl_xor(q0, 8); q1 += __shfl_xor(q1, 8);
    if (lane == 0) {
        out[(size_t)i * 2 + 0] = q0 + bfc[0];
        out[(size_t)i * 2 + 1] = q1 + bfc[1];
    }
}

// ---------------------------------------------------------------------------
extern "C" void kernel_launch(void* const* d_in, const int* in_sizes, int n_in,
                              void* d_out, int out_size, void* d_ws, size_t ws_size,
                              hipStream_t stream) {
    const float* x    = (const float*)d_in[0];
    const int*   ei   = (const int*)d_in[1];
    const float* Wl1  = (const float*)d_in[2];
    const float* bl1  = (const float*)d_in[3];
    const float* Wr1  = (const float*)d_in[4];
    const float* br1  = (const float*)d_in[5];
    const float* att1 = (const float*)d_in[6];
    const float* b1   = (const float*)d_in[7];
    const float* Wl2  = (const float*)d_in[8];
    const float* bl2  = (const float*)d_in[9];
    const float* Wr2  = (const float*)d_in[10];
    const float* br2  = (const float*)d_in[11];
    const float* att2 = (const float*)d_in[12];
    const float* b2   = (const float*)d_in[13];
    const float* Wl3  = (const float*)d_in[14];
    const float* bl3  = (const float*)d_in[15];
    const float* Wr3  = (const float*)d_in[16];
    const float* br3  = (const float*)d_in[17];
    const float* att3 = (const float*)d_in[18];
    const float* b3   = (const float*)d_in[19];
    const float* Wfc  = (const float*)d_in[20];
    const float* bfc  = (const float*)d_in[21];
    float* out = (float*)d_out;

    const int N = in_sizes[0] / 16;   // 30000
    const int E = in_sizes[1] / 2;    // 480000
    const int* srcp = ei;
    const int* dstp = ei + E;

    char* ws = (char*)d_ws;
    size_t off = 0;
    auto take = [&](size_t bytes) -> char* {
        char* p = ws + off;
        off = (off + bytes + 255) & ~(size_t)255;
        return p;
    };
    const int nb = (N + 1023) / 1024;
    int* rowptr = (int*)take((size_t)(N + 1) * 4);
    int* cursor = (int*)take((size_t)N * 4);
    int* deg    = (int*)take((size_t)N * 4);
    int* excl   = (int*)take((size_t)N * 4);
    int* bsum   = (int*)take((size_t)(nb + 1) * 4);
    int* col    = (int*)take((size_t)(E + N + 64) * 4);
    unsigned short* xlb = (unsigned short*)take((size_t)N * 256 * 2);
    float* xr   = (float*)take((size_t)N * 256 * 4);
    unsigned short* Hh = (unsigned short*)take((size_t)N * 256 * 2);
    unsigned short* Hl = (unsigned short*)take((size_t)N * 256 * 2);
    unsigned short* W2lh = (unsigned short*)take(256 * 256 * 2);
    unsigned short* W2ll = (unsigned short*)take(256 * 256 * 2);
    unsigned short* W2rh = (unsigned short*)take(256 * 256 * 2);
    unsigned short* W2rl = (unsigned short*)take(256 * 256 * 2);
    unsigned short* W3lh = (unsigned short*)take(256 * 64 * 2);
    unsigned short* W3ll = (unsigned short*)take(256 * 64 * 2);
    unsigned short* W3rh = (unsigned short*)take(256 * 64 * 2);
    unsigned short* W3rl = (unsigned short*)take(256 * 64 * 2);
    (void)ws_size; (void)n_in; (void)out_size;

    // fused prep: deg init + 4 weight conversions
    {
        int total = N + 65536 + 65536 + 16384 + 16384;
        k_prep<<<dim3((total + 255) / 256), dim3(256), 0, stream>>>(
            deg, N, Wl2, Wr2, Wl3, Wr3,
            W2lh, W2ll, W2rh, W2rl, W3lh, W3ll, W3rh, W3rl);
    }
    k_count<<<dim3((E + 255) / 256), dim3(256), 0, stream>>>(dstp, E, deg);
    k_scan1<<<dim3(nb), dim3(1024), 0, stream>>>(deg, excl, bsum, N);
    k_scan23<<<dim3(nb), dim3(1024), 0, stream>>>(excl, bsum, rowptr, cursor, N, nb);
    k_scatter<<<dim3((E + N + 64 + 255) / 256), dim3(256), 0, stream>>>(srcp, dstp, E, N, cursor, col);

    dim3 agg_grid(N);
    int mblk = (N + 127) / 128;

    // layer 1 (K=16): fused dual f32 GEMM (xl -> bf16, xr -> f32)
    gemm_bias2<<<dim3(4, (N + 63) / 64), dim3(256), 0, stream>>>(
        x, Wl1, bl1, Wr1, br1, xlb, xr, N, 16, 256);
    gat_agg4<<<agg_grid, dim3(64), 0, stream>>>(xlb, xr, att1, b1, rowptr, col, Hh, Hl, N);

    // layer 2 (K=256, NC=256): LDS-staged dual bf16x3 MFMA GEMM
    gemm_dual<2><<<dim3(2, mblk), dim3(512), 0, stream>>>(
        Hh, Hl, W2lh, W2ll, W2rh, W2rl, bl2, br2, xlb, xr, N, 256);
    gat_agg4<<<agg_grid, dim3(64), 0, stream>>>(xlb, xr, att2, b2, rowptr, col, Hh, Hl, N);

    // layer 3 (K=256, NC=64): dual MFMA GEMM + fused agg/FC
    gemm_dual<1><<<dim3(1, mblk), dim3(512), 0, stream>>>(
        Hh, Hl, W3lh, W3ll, W3rh, W3rl, bl3, br3, xlb, xr, N, 64);
    gat_agg1_fc<<<agg_grid, dim3(64), 0, stream>>>(xlb, xr, att3, b3, Wfc, bfc, rowptr, col, out, N);
}